// Round 1
// baseline (606.379 us; speedup 1.0000x reference)
//
#include <hip/hip_runtime.h>

#define HID 64
#define DIN 128

// ---------------- degree / norm ----------------

__global__ __launch_bounds__(256) void k_init(float* deg, int* cnt, int n) {
  int i = blockIdx.x * 256 + threadIdx.x;
  if (i < n) { deg[i] = 1.0f; cnt[i] = 0; }  // self-loop weight 1.0 pre-seeded
}

__global__ __launch_bounds__(256) void k_degcnt(const int* __restrict__ dst,
                                                const float* __restrict__ ew,
                                                float* deg, int* cnt, int E) {
  int e = blockIdx.x * 256 + threadIdx.x;
  if (e < E) {
    int d = dst[e];
    atomicAdd(&deg[d], ew[e]);
    atomicAdd(&cnt[d], 1);
  }
}

__global__ __launch_bounds__(256) void k_dinv(const float* __restrict__ deg, float* dinv, int n) {
  int i = blockIdx.x * 256 + threadIdx.x;
  if (i < n) { float d = deg[i]; dinv[i] = (d > 0.f) ? rsqrtf(d) : 0.f; }
}

// ---------------- scan (counts -> row offsets), 1024 elems per chunk ----------------

__global__ __launch_bounds__(256) void k_chunksum(const int* __restrict__ cnt, int* bsum, int n) {
  int b = blockIdx.x, t = threadIdx.x;
  int base = b * 1024;
  int s = 0;
  for (int i = t; i < 1024; i += 256) {
    int g = base + i;
    s += (g < n) ? cnt[g] : 0;
  }
  __shared__ int red[4];
  for (int o = 32; o > 0; o >>= 1) s += __shfl_down(s, o);
  if ((t & 63) == 0) red[t >> 6] = s;
  __syncthreads();
  if (t == 0) bsum[b] = red[0] + red[1] + red[2] + red[3];
}

// exclusive scan of <=64 block sums with one wave; writes grand total to *totN (= offs[N])
__global__ __launch_bounds__(64) void k_scanbsum(int* bsum, int nb, int* totN) {
  int lane = threadIdx.x;
  int v = (lane < nb) ? bsum[lane] : 0;
  int incl = v;
  for (int o = 1; o < 64; o <<= 1) {
    int u = __shfl_up(incl, o);
    if (lane >= o) incl += u;
  }
  if (lane < nb) bsum[lane] = incl - v;   // exclusive
  if (lane == 63) *totN = incl;
}

__global__ __launch_bounds__(256) void k_scanfinal(const int* __restrict__ cnt,
                                                   const int* __restrict__ bsum,
                                                   int* offs, int* cursor, int n) {
  int b = blockIdx.x, t = threadIdx.x;
  int i0 = b * 1024 + t * 4;
  int v[4], tsum = 0;
#pragma unroll
  for (int k = 0; k < 4; ++k) {
    v[k] = (i0 + k < n) ? cnt[i0 + k] : 0;
    tsum += v[k];
  }
  int incl = tsum;
  for (int o = 1; o < 64; o <<= 1) {
    int u = __shfl_up(incl, o);
    if ((t & 63) >= o) incl += u;
  }
  int wexcl = incl - tsum;
  __shared__ int wtot[4];
  int w = t >> 6;
  if ((t & 63) == 63) wtot[w] = incl;
  __syncthreads();
  int wbase = 0;
  for (int i = 0; i < w; ++i) wbase += wtot[i];
  int run = bsum[b] + wbase + wexcl;
#pragma unroll
  for (int k = 0; k < 4; ++k) {
    if (i0 + k < n) { offs[i0 + k] = run; cursor[i0 + k] = run; }
    run += v[k];
  }
}

// ---------------- CSR fill (dst-sorted edges, precomputed norm) ----------------

__global__ __launch_bounds__(256) void k_fill(const int* __restrict__ src,
                                              const int* __restrict__ dst,
                                              const float* __restrict__ ew,
                                              const float* __restrict__ dinv,
                                              int* cursor, int* src_s, float* norm_s, int E) {
  int e = blockIdx.x * 256 + threadIdx.x;
  if (e < E) {
    int s = src[e], d = dst[e];
    int pos = atomicAdd(&cursor[d], 1);
    src_s[pos] = s;
    norm_s[pos] = dinv[s] * ew[e] * dinv[d];
  }
}

// ---------------- GEMM: out[N][64] = X[N][K] @ W[64][K]^T ----------------
// 64-node x 64-feature block tile; both operands staged k-major in LDS so the
// inner loop is two conflict-free b128 reads + 16 FMA per k-step.

template <int K>
__global__ __launch_bounds__(256) void k_gemm(const float* __restrict__ X,
                                              const float* __restrict__ W,
                                              float* __restrict__ out, int n_nodes) {
  constexpr int PAD = 68;                 // float4-aligned, breaks b128 bank aliasing
  __shared__ float WT[64 * PAD];          // WT[d][j]
  __shared__ float XT[64 * PAD];          // XT[d][m]
  const int tid = threadIdx.x;
  const int n0 = blockIdx.x * 64;
  const int tx = tid & 15;                // feature group: j = 4*tx + ji
  const int ty = tid >> 4;                // node group:    m = 4*ty + mi
  float acc[4][4] = {{0.f}};

  for (int ph = 0; ph < K / 64; ++ph) {
    __syncthreads();
    for (int idx = tid; idx < 64 * 64; idx += 256) {
      int j = idx >> 6, d = idx & 63;     // coalesced global reads (d fastest)
      WT[d * PAD + j] = W[j * K + ph * 64 + d];
      int n = n0 + j;
      XT[d * PAD + j] = (n < n_nodes) ? X[(size_t)n * K + ph * 64 + d] : 0.f;
    }
    __syncthreads();
#pragma unroll 4
    for (int d = 0; d < 64; ++d) {
      float4 wv = *reinterpret_cast<const float4*>(&WT[d * PAD + 4 * tx]);
      float4 xv = *reinterpret_cast<const float4*>(&XT[d * PAD + 4 * ty]);
      float xs[4] = {xv.x, xv.y, xv.z, xv.w};
      float ws[4] = {wv.x, wv.y, wv.z, wv.w};
#pragma unroll
      for (int mi = 0; mi < 4; ++mi)
#pragma unroll
        for (int ji = 0; ji < 4; ++ji)
          acc[mi][ji] = fmaf(xs[mi], ws[ji], acc[mi][ji]);
    }
  }

#pragma unroll
  for (int mi = 0; mi < 4; ++mi) {
    int n = n0 + 4 * ty + mi;
    if (n < n_nodes) {
      float4 o = make_float4(acc[mi][0], acc[mi][1], acc[mi][2], acc[mi][3]);
      *reinterpret_cast<float4*>(&out[(size_t)n * HID + 4 * tx]) = o;
    }
  }
}

// ---------------- aggregation: one wave per node, lane = feature ----------------
// mode 0: out = relu(agg + bias)          (layer 1 -> h1)
// mode 1: out = agg + bias + resid        (layer 2 -> final)

__global__ __launch_bounds__(256) void k_agg(const float* __restrict__ h,
                                             const int* __restrict__ offs,
                                             const int* __restrict__ src_s,
                                             const float* __restrict__ norm_s,
                                             const float* __restrict__ dinv,
                                             const float* __restrict__ bias,
                                             const float* __restrict__ resid,
                                             float* __restrict__ out, int n_nodes, int mode) {
  int gw = (blockIdx.x * 256 + threadIdx.x) >> 6;  // node id
  int j = threadIdx.x & 63;                        // feature
  if (gw >= n_nodes) return;
  int beg = offs[gw], end = offs[gw + 1];
  float di = dinv[gw];
  float acc = h[(size_t)gw * HID + j] * (di * di);  // self loop (weight 1.0)
  float acc2 = 0.f;
  int k = beg;
  for (; k + 2 <= end; k += 2) {                    // 2 gathers in flight
    int s0 = src_s[k], s1 = src_s[k + 1];
    float w0 = norm_s[k], w1 = norm_s[k + 1];
    acc  = fmaf(h[(size_t)s0 * HID + j], w0, acc);
    acc2 = fmaf(h[(size_t)s1 * HID + j], w1, acc2);
  }
  if (k < end) acc = fmaf(h[(size_t)src_s[k] * HID + j], norm_s[k], acc);
  acc += acc2 + bias[j];
  if (mode == 0) acc = fmaxf(acc, 0.f);
  else acc += resid[(size_t)gw * HID + j];
  out[(size_t)gw * HID + j] = acc;
}

// ---------------- launcher ----------------

extern "C" void kernel_launch(void* const* d_in, const int* in_sizes, int n_in,
                              void* d_out, int out_size, void* d_ws, size_t ws_size,
                              hipStream_t stream) {
  const float* x  = (const float*)d_in[0];
  const int*   ei = (const int*)d_in[1];
  const float* ew = (const float*)d_in[2];
  const float* W1 = (const float*)d_in[3];
  const float* b1 = (const float*)d_in[4];
  const float* W2 = (const float*)d_in[5];
  const float* b2 = (const float*)d_in[6];
  float* out = (float*)d_out;

  const int N = in_sizes[0] / DIN;
  const int E = in_sizes[2];
  const int* src = ei;        // ei shape (2,E) row-major
  const int* dst = ei + E;

  char* p = (char*)d_ws;
  auto carve = [&](size_t bytes) {
    char* r = p;
    p += (bytes + 255) & ~(size_t)255;
    return r;
  };
  float* deg    = (float*)carve((size_t)N * 4);
  float* dinv   = (float*)carve((size_t)N * 4);
  int*   cnt    = (int*)carve((size_t)N * 4);
  int*   offs   = (int*)carve((size_t)(N + 1) * 4);
  int*   cursor = (int*)carve((size_t)N * 4);
  int*   bsum   = (int*)carve(64 * 4);
  int*   src_s  = (int*)carve((size_t)E * 4);
  float* norm_s = (float*)carve((size_t)E * 4);
  float* h      = (float*)carve((size_t)N * HID * 4);
  float* h1     = (float*)carve((size_t)N * HID * 4);

  int nbN = (N + 255) / 256;
  int nbE = (E + 255) / 256;
  int nchunk = (N + 1023) / 1024;   // 49 <= 64, fits the one-wave scan
  int gblk = (N + 63) / 64;
  int ablk = (N + 3) / 4;

  k_init<<<nbN, 256, 0, stream>>>(deg, cnt, N);
  k_degcnt<<<nbE, 256, 0, stream>>>(dst, ew, deg, cnt, E);
  k_dinv<<<nbN, 256, 0, stream>>>(deg, dinv, N);
  k_chunksum<<<nchunk, 256, 0, stream>>>(cnt, bsum, N);
  k_scanbsum<<<1, 64, 0, stream>>>(bsum, nchunk, offs + N);
  k_scanfinal<<<nchunk, 256, 0, stream>>>(cnt, bsum, offs, cursor, N);
  k_fill<<<nbE, 256, 0, stream>>>(src, dst, ew, dinv, cursor, src_s, norm_s, E);

  // layer 1
  k_gemm<DIN><<<gblk, 256, 0, stream>>>(x, W1, h, N);
  k_agg<<<ablk, 256, 0, stream>>>(h, offs, src_s, norm_s, dinv, b1, nullptr, h1, N, 0);
  // layer 2 (reuse h buffer for h1 @ W2^T)
  k_gemm<HID><<<gblk, 256, 0, stream>>>(h1, W2, h, N);
  k_agg<<<ablk, 256, 0, stream>>>(h, offs, src_s, norm_s, dinv, b2, h1, out, N, 1);
}

// Round 2
// 382.865 us; speedup vs baseline: 1.5838x; 1.5838x over previous
//
#include <hip/hip_runtime.h>

#define HID 64
#define DIN 128
#define CAP 80                  // slots per node; P(deg>=80)~7e-16 for Poisson(32)
#define FIXS 16777216.0f        // 2^24 fixed-point scale for weighted degree

typedef unsigned long long ull;

// ---------------- init: packed[n] = (count=0)<<32 | fix(1.0) (self-loop weight) ----------------

__global__ __launch_bounds__(256) void k_init(ull* packed, int n) {
  int i = blockIdx.x * 256 + threadIdx.x;
  if (i < n) packed[i] = (ull)16777216u;   // count 0, deg 1.0 (self loop)
}

// ---------------- single-pass build: one 64-bit atomic per edge ----------------
// old = atomicAdd(packed[d], 1<<32 | fix(ew)); slot = old>>32; store (src, ew).

__global__ __launch_bounds__(256) void k_build(const int* __restrict__ src,
                                               const int* __restrict__ dst,
                                               const float* __restrict__ ew,
                                               ull* packed, int2* slots, int E) {
  int e = blockIdx.x * 256 + threadIdx.x;
  if (e < E) {
    int s = src[e], d = dst[e];
    float w = ew[e];
    ull inc = ((ull)1 << 32) | (ull)(unsigned)(w * FIXS + 0.5f);
    ull old = atomicAdd(&packed[d], inc);
    int pos = (int)(old >> 32);
    if (pos < CAP) {
      slots[(size_t)d * CAP + pos] = make_int2(s, __float_as_int(w));
    }
  }
}

// ---------------- unpack: cnt + dinv ----------------

__global__ __launch_bounds__(256) void k_dinv(const ull* __restrict__ packed,
                                              int* cnt, float* dinv, int n) {
  int i = blockIdx.x * 256 + threadIdx.x;
  if (i < n) {
    ull p = packed[i];
    int c = (int)(p >> 32);
    cnt[i] = (c < CAP) ? c : CAP;
    float deg = (float)(unsigned)(p & 0xffffffffULL) * (1.0f / FIXS);
    dinv[i] = (deg > 0.f) ? rsqrtf(deg) : 0.f;
  }
}

// ---------------- GEMM: out[N][64] = X[N][K] @ W[64][K]^T ----------------

template <int K>
__global__ __launch_bounds__(256) void k_gemm(const float* __restrict__ X,
                                              const float* __restrict__ W,
                                              float* __restrict__ out, int n_nodes) {
  constexpr int PAD = 68;
  __shared__ float WT[64 * PAD];          // WT[d][j]
  __shared__ float XT[64 * PAD];          // XT[d][m]
  const int tid = threadIdx.x;
  const int n0 = blockIdx.x * 64;
  const int tx = tid & 15;                // feature group: j = 4*tx + ji
  const int ty = tid >> 4;                // node group:    m = 4*ty + mi
  float acc[4][4] = {{0.f}};

  for (int ph = 0; ph < K / 64; ++ph) {
    __syncthreads();
    for (int idx = tid; idx < 64 * 64; idx += 256) {
      int j = idx >> 6, d = idx & 63;     // coalesced global reads (d fastest)
      WT[d * PAD + j] = W[j * K + ph * 64 + d];
      int n = n0 + j;
      XT[d * PAD + j] = (n < n_nodes) ? X[(size_t)n * K + ph * 64 + d] : 0.f;
    }
    __syncthreads();
#pragma unroll 4
    for (int d = 0; d < 64; ++d) {
      float4 wv = *reinterpret_cast<const float4*>(&WT[d * PAD + 4 * tx]);
      float4 xv = *reinterpret_cast<const float4*>(&XT[d * PAD + 4 * ty]);
      float xs[4] = {xv.x, xv.y, xv.z, xv.w};
      float ws[4] = {wv.x, wv.y, wv.z, wv.w};
#pragma unroll
      for (int mi = 0; mi < 4; ++mi)
#pragma unroll
        for (int ji = 0; ji < 4; ++ji)
          acc[mi][ji] = fmaf(xs[mi], ws[ji], acc[mi][ji]);
    }
  }

#pragma unroll
  for (int mi = 0; mi < 4; ++mi) {
    int n = n0 + 4 * ty + mi;
    if (n < n_nodes) {
      float4 o = make_float4(acc[mi][0], acc[mi][1], acc[mi][2], acc[mi][3]);
      *reinterpret_cast<float4*>(&out[(size_t)n * HID + 4 * tx]) = o;
    }
  }
}

// ---------------- aggregation: one wave per node, lane = feature ----------------
// Batch: lane l loads edge record l (coalesced int2), computes its norm, then
// shfl-broadcasts (src, norm) into the lane=feature FMA loop.
// mode 0: out = relu(agg + bias)          (layer 1 -> h1)
// mode 1: out = agg + bias + resid        (layer 2 -> final)

__global__ __launch_bounds__(256) void k_agg(const float* __restrict__ h,
                                             const int2* __restrict__ slots,
                                             const int* __restrict__ cnt,
                                             const float* __restrict__ dinv,
                                             const float* __restrict__ bias,
                                             const float* __restrict__ resid,
                                             float* __restrict__ out, int n_nodes, int mode) {
  int gw = (blockIdx.x * 256 + threadIdx.x) >> 6;  // node id
  int j = threadIdx.x & 63;                        // feature (= lane)
  if (gw >= n_nodes) return;
  int m = cnt[gw];
  float di = dinv[gw];
  float acc = h[(size_t)gw * HID + j] * (di * di);  // self loop (weight 1.0)
  float acc2 = 0.f;
  const size_t base = (size_t)gw * CAP;

  for (int b0 = 0; b0 < m; b0 += 64) {
    int l = b0 + j;                                // lane = edge index in batch
    int s = 0; float nrm = 0.f;
    if (l < m) {
      int2 r = slots[base + l];
      s = r.x;
      nrm = dinv[s] * __int_as_float(r.y) * di;
    }
    int lim = m - b0; if (lim > 64) lim = 64;
    int i = 0;
    for (; i + 2 <= lim; i += 2) {
      int s0 = __shfl(s, i);     float w0 = __shfl(nrm, i);
      int s1 = __shfl(s, i + 1); float w1 = __shfl(nrm, i + 1);
      acc  = fmaf(h[(size_t)s0 * HID + j], w0, acc);
      acc2 = fmaf(h[(size_t)s1 * HID + j], w1, acc2);
    }
    if (i < lim) {
      int s0 = __shfl(s, i); float w0 = __shfl(nrm, i);
      acc = fmaf(h[(size_t)s0 * HID + j], w0, acc);
    }
  }
  acc += acc2 + bias[j];
  if (mode == 0) acc = fmaxf(acc, 0.f);
  else acc += resid[(size_t)gw * HID + j];
  out[(size_t)gw * HID + j] = acc;
}

// ---------------- launcher ----------------

extern "C" void kernel_launch(void* const* d_in, const int* in_sizes, int n_in,
                              void* d_out, int out_size, void* d_ws, size_t ws_size,
                              hipStream_t stream) {
  const float* x  = (const float*)d_in[0];
  const int*   ei = (const int*)d_in[1];
  const float* ew = (const float*)d_in[2];
  const float* W1 = (const float*)d_in[3];
  const float* b1 = (const float*)d_in[4];
  const float* W2 = (const float*)d_in[5];
  const float* b2 = (const float*)d_in[6];
  float* out = (float*)d_out;

  const int N = in_sizes[0] / DIN;
  const int E = in_sizes[2];
  const int* src = ei;        // ei shape (2,E) row-major
  const int* dst = ei + E;

  char* p = (char*)d_ws;
  auto carve = [&](size_t bytes) {
    char* r = p;
    p += (bytes + 255) & ~(size_t)255;
    return r;
  };
  ull*   packed = (ull*)carve((size_t)N * 8);
  int*   cnt    = (int*)carve((size_t)N * 4);
  float* dinv   = (float*)carve((size_t)N * 4);
  int2*  slots  = (int2*)carve((size_t)N * CAP * 8);
  float* h      = (float*)carve((size_t)N * HID * 4);
  float* h1     = (float*)carve((size_t)N * HID * 4);

  int nbN = (N + 255) / 256;
  int nbE = (E + 255) / 256;
  int gblk = (N + 63) / 64;
  int ablk = (N + 3) / 4;

  k_init<<<nbN, 256, 0, stream>>>(packed, N);
  k_build<<<nbE, 256, 0, stream>>>(src, dst, ew, packed, slots, E);
  k_dinv<<<nbN, 256, 0, stream>>>(packed, cnt, dinv, N);

  // layer 1
  k_gemm<DIN><<<gblk, 256, 0, stream>>>(x, W1, h, N);
  k_agg<<<ablk, 256, 0, stream>>>(h, slots, cnt, dinv, b1, nullptr, h1, N, 0);
  // layer 2 (reuse h buffer for h1 @ W2^T)
  k_gemm<HID><<<gblk, 256, 0, stream>>>(h1, W2, h, N);
  k_agg<<<ablk, 256, 0, stream>>>(h, slots, cnt, dinv, b2, h1, out, N, 1);
}

// Round 3
// 318.862 us; speedup vs baseline: 1.9017x; 1.2007x over previous
//
#include <hip/hip_runtime.h>

#define HID 64
#define DIN 128
#define NBLK 512                // blocks for hist/scatter passes

typedef unsigned long long ull;

// ============ build pass A: coarse histogram (bucket = dst>>8) ============

__global__ __launch_bounds__(256) void k_histA(const int* __restrict__ dst,
                                               int* __restrict__ G,
                                               int E, int NBC, int chunk) {
  __shared__ int h[256];
  int b = blockIdx.x, tid = threadIdx.x;
  h[tid] = 0;
  __syncthreads();
  int e0 = b * chunk, e1 = min(E, e0 + chunk);
  for (int e = e0 + tid; e < e1; e += 256) atomicAdd(&h[dst[e] >> 8], 1);
  __syncthreads();
  if (tid < NBC) G[tid * NBLK + b] = h[tid];   // bin-major for counting-sort scan
}

// ============ exclusive scan of G (L = NBC*NBLK elems), chunk=2048 ============

__global__ __launch_bounds__(256) void k_chunksum(const int* __restrict__ G, int* bsum, int L) {
  int b = blockIdx.x, t = threadIdx.x;
  int base = b * 2048;
  int s = 0;
  for (int i = t; i < 2048; i += 256) {
    int g = base + i;
    s += (g < L) ? G[g] : 0;
  }
  __shared__ int red[4];
  for (int o = 32; o > 0; o >>= 1) s += __shfl_down(s, o);
  if ((t & 63) == 0) red[t >> 6] = s;
  __syncthreads();
  if (t == 0) bsum[b] = red[0] + red[1] + red[2] + red[3];
}

__global__ __launch_bounds__(64) void k_scanbsum(int* bsum, int nb) {
  int lane = threadIdx.x;
  int v = (lane < nb) ? bsum[lane] : 0;
  int incl = v;
  for (int o = 1; o < 64; o <<= 1) {
    int u = __shfl_up(incl, o);
    if (lane >= o) incl += u;
  }
  if (lane < nb) bsum[lane] = incl - v;   // exclusive
}

__global__ __launch_bounds__(256) void k_scanfinal(int* G, const int* __restrict__ bsum, int L) {
  int b = blockIdx.x, t = threadIdx.x;
  int i0 = b * 2048 + t * 8;
  int v[8], tsum = 0;
#pragma unroll
  for (int k = 0; k < 8; ++k) {
    v[k] = (i0 + k < L) ? G[i0 + k] : 0;
    tsum += v[k];
  }
  int incl = tsum;
  for (int o = 1; o < 64; o <<= 1) {
    int u = __shfl_up(incl, o);
    if ((t & 63) >= o) incl += u;
  }
  int wexcl = incl - tsum;
  __shared__ int wtot[4];
  int w = t >> 6;
  if ((t & 63) == 63) wtot[w] = incl;
  __syncthreads();
  int wbase = 0;
  for (int i = 0; i < w; ++i) wbase += wtot[i];
  int run = bsum[b] + wbase + wexcl;
#pragma unroll
  for (int k = 0; k < 8; ++k) {
    if (i0 + k < L) G[i0 + k] = run;      // in-place: v[] already read
    run += v[k];
  }
}

// ============ pass A scatter: coarse-bucketed records, LDS cursors ============
// record int2 = ( float_bits(ew), (src<<16)|dst )

__global__ __launch_bounds__(256) void k_scatterA(const int* __restrict__ src,
                                                  const int* __restrict__ dst,
                                                  const float* __restrict__ ew,
                                                  const int* __restrict__ Gs,
                                                  int2* __restrict__ bufA,
                                                  int E, int NBC, int chunk) {
  __shared__ int cur[256];                 // NBC <= 256 (N <= 65536)
  int b = blockIdx.x, tid = threadIdx.x;
  if (tid < NBC) cur[tid] = Gs[tid * NBLK + b];   // this block's reserved run per bucket
  __syncthreads();
  int e0 = b * chunk, e1 = min(E, e0 + chunk);
  for (int e = e0 + tid; e < e1; e += 256) {
    int s = src[e], d = dst[e];
    float w = ew[e];
    int p = atomicAdd(&cur[d >> 8], 1);
    bufA[p] = make_int2(__float_as_int(w), (int)(((unsigned)s << 16) | (unsigned)d));
  }
}

// ============ pass B: one block per coarse bucket -> dst-grouped + offs + dinv ============

__global__ __launch_bounds__(256) void k_passB(const int2* __restrict__ bufA,
                                               const int* __restrict__ Gs,
                                               int2* __restrict__ bufB,
                                               int* __restrict__ offs,
                                               float* __restrict__ dinv,
                                               int NBC, int E, int N) {
  int bin = blockIdx.x, tid = threadIdx.x;
  __shared__ int h2[256];
  __shared__ int cur[256];
  __shared__ float dg[256];
  int base = Gs[bin * NBLK];
  int end  = (bin + 1 < NBC) ? Gs[(bin + 1) * NBLK] : E;
  int m = end - base;
  h2[tid] = 0;
  dg[tid] = 0.f;
  __syncthreads();
  // phase 1: fine histogram of dst&255
  for (int i = tid; i < m; i += 256) {
    unsigned sd = (unsigned)bufA[base + i].y;
    atomicAdd(&h2[sd & 255], 1);
  }
  __syncthreads();
  int own = h2[tid];
  // inclusive Hillis-Steele scan over 256 bins
  for (int o = 1; o < 256; o <<= 1) {
    int u = (tid >= o) ? h2[tid - o] : 0;
    __syncthreads();
    h2[tid] += u;
    __syncthreads();
  }
  int excl = h2[tid] - own;
  cur[tid] = excl;
  int nd = (bin << 8) + tid;
  if (nd < N) offs[nd] = base + excl;
  if (bin == NBC - 1 && tid == 0) offs[N] = E;
  __syncthreads();
  // phase 2: scatter into dst-grouped order + weighted degree
  for (int i = tid; i < m; i += 256) {
    int2 r = bufA[base + i];
    unsigned sd = (unsigned)r.y;
    int dl = (int)(sd & 255u);
    int p = atomicAdd(&cur[dl], 1);
    bufB[base + p] = r;
    atomicAdd(&dg[dl], __int_as_float(r.x));
  }
  __syncthreads();
  if (nd < N) dinv[nd] = rsqrtf(1.0f + dg[tid]);   // self-loop weight 1.0; deg>=1
}

// ============ GEMM: out[N][64] = X[N][K] @ W[64][K]^T ============

template <int K>
__global__ __launch_bounds__(256) void k_gemm(const float* __restrict__ X,
                                              const float* __restrict__ W,
                                              float* __restrict__ out, int n_nodes) {
  constexpr int PAD = 68;
  __shared__ float WT[64 * PAD];          // WT[d][j]
  __shared__ float XT[64 * PAD];          // XT[d][m]
  const int tid = threadIdx.x;
  const int n0 = blockIdx.x * 64;
  const int tx = tid & 15;                // feature group: j = 4*tx + ji
  const int ty = tid >> 4;                // node group:    m = 4*ty + mi
  float acc[4][4] = {{0.f}};

  for (int ph = 0; ph < K / 64; ++ph) {
    __syncthreads();
    for (int idx = tid; idx < 64 * 64; idx += 256) {
      int j = idx >> 6, d = idx & 63;     // coalesced global reads (d fastest)
      WT[d * PAD + j] = W[j * K + ph * 64 + d];
      int n = n0 + j;
      XT[d * PAD + j] = (n < n_nodes) ? X[(size_t)n * K + ph * 64 + d] : 0.f;
    }
    __syncthreads();
#pragma unroll 4
    for (int d = 0; d < 64; ++d) {
      float4 wv = *reinterpret_cast<const float4*>(&WT[d * PAD + 4 * tx]);
      float4 xv = *reinterpret_cast<const float4*>(&XT[d * PAD + 4 * ty]);
      float xs[4] = {xv.x, xv.y, xv.z, xv.w};
      float ws[4] = {wv.x, wv.y, wv.z, wv.w};
#pragma unroll
      for (int mi = 0; mi < 4; ++mi)
#pragma unroll
        for (int ji = 0; ji < 4; ++ji)
          acc[mi][ji] = fmaf(xs[mi], ws[ji], acc[mi][ji]);
    }
  }

#pragma unroll
  for (int mi = 0; mi < 4; ++mi) {
    int n = n0 + 4 * ty + mi;
    if (n < n_nodes) {
      float4 o = make_float4(acc[mi][0], acc[mi][1], acc[mi][2], acc[mi][3]);
      *reinterpret_cast<float4*>(&out[(size_t)n * HID + 4 * tx]) = o;
    }
  }
}

// ============ aggregation: one wave per node, lane = feature ============
// Batch: lane l loads edge record l (coalesced int2), computes its norm, then
// shfl-broadcasts (src, norm) into the lane=feature FMA loop.
// mode 0: out = relu(agg + bias)          (layer 1 -> h1)
// mode 1: out = agg + bias + resid        (layer 2 -> final)

__global__ __launch_bounds__(256) void k_agg(const float* __restrict__ h,
                                             const int2* __restrict__ recs,
                                             const int* __restrict__ offs,
                                             const float* __restrict__ dinv,
                                             const float* __restrict__ bias,
                                             const float* __restrict__ resid,
                                             float* __restrict__ out, int n_nodes, int mode) {
  int gw = (blockIdx.x * 256 + threadIdx.x) >> 6;  // node id
  int j = threadIdx.x & 63;                        // feature (= lane)
  if (gw >= n_nodes) return;
  int beg = offs[gw], end = offs[gw + 1];
  int m = end - beg;
  float di = dinv[gw];
  float acc = h[(size_t)gw * HID + j] * (di * di);  // self loop (weight 1.0)
  float acc2 = 0.f;

  for (int b0 = 0; b0 < m; b0 += 64) {
    int l = b0 + j;                                // lane = edge index in batch
    int s = 0; float nrm = 0.f;
    if (l < m) {
      int2 r = recs[beg + l];
      s = (int)(((unsigned)r.y) >> 16);
      nrm = dinv[s] * __int_as_float(r.x) * di;
    }
    int lim = m - b0; if (lim > 64) lim = 64;
    int i = 0;
    for (; i + 2 <= lim; i += 2) {
      int s0 = __shfl(s, i);     float w0 = __shfl(nrm, i);
      int s1 = __shfl(s, i + 1); float w1 = __shfl(nrm, i + 1);
      acc  = fmaf(h[(size_t)s0 * HID + j], w0, acc);
      acc2 = fmaf(h[(size_t)s1 * HID + j], w1, acc2);
    }
    if (i < lim) {
      int s0 = __shfl(s, i); float w0 = __shfl(nrm, i);
      acc = fmaf(h[(size_t)s0 * HID + j], w0, acc);
    }
  }
  acc += acc2 + bias[j];
  if (mode == 0) acc = fmaxf(acc, 0.f);
  else acc += resid[(size_t)gw * HID + j];
  out[(size_t)gw * HID + j] = acc;
}

// ============ launcher ============

extern "C" void kernel_launch(void* const* d_in, const int* in_sizes, int n_in,
                              void* d_out, int out_size, void* d_ws, size_t ws_size,
                              hipStream_t stream) {
  const float* x  = (const float*)d_in[0];
  const int*   ei = (const int*)d_in[1];
  const float* ew = (const float*)d_in[2];
  const float* W1 = (const float*)d_in[3];
  const float* b1 = (const float*)d_in[4];
  const float* W2 = (const float*)d_in[5];
  const float* b2 = (const float*)d_in[6];
  float* out = (float*)d_out;

  const int N = in_sizes[0] / DIN;
  const int E = in_sizes[2];
  const int* src = ei;        // ei shape (2,E) row-major
  const int* dst = ei + E;

  const int NBC = (N + 255) >> 8;          // coarse buckets (196 for N=50000)
  const int L = NBC * NBLK;                // G length
  const int chunk = (E + NBLK - 1) / NBLK;
  const int nch = (L + 2047) / 2048;       // scan chunks (<=64)

  char* p = (char*)d_ws;
  auto carve = [&](size_t bytes) {
    char* r = p;
    p += (bytes + 255) & ~(size_t)255;
    return r;
  };
  int*   G     = (int*)carve((size_t)L * 4);
  int*   bsum  = (int*)carve(64 * 4);
  int*   offs  = (int*)carve((size_t)(N + 1) * 4);
  float* dinv  = (float*)carve((size_t)N * 4);
  int2*  bufA  = (int2*)carve((size_t)E * 8);
  int2*  bufB  = (int2*)carve((size_t)E * 8);
  float* h     = (float*)carve((size_t)N * HID * 4);
  float* h1    = (float*)carve((size_t)N * HID * 4);

  int gblk = (N + 63) / 64;
  int ablk = (N + 3) / 4;

  // ---- build (zero global atomics) ----
  k_histA<<<NBLK, 256, 0, stream>>>(dst, G, E, NBC, chunk);
  k_chunksum<<<nch, 256, 0, stream>>>(G, bsum, L);
  k_scanbsum<<<1, 64, 0, stream>>>(bsum, nch);
  k_scanfinal<<<nch, 256, 0, stream>>>(G, bsum, L);
  k_scatterA<<<NBLK, 256, 0, stream>>>(src, dst, ew, G, bufA, E, NBC, chunk);
  k_passB<<<NBC, 256, 0, stream>>>(bufA, G, bufB, offs, dinv, NBC, E, N);

  // ---- layer 1 ----
  k_gemm<DIN><<<gblk, 256, 0, stream>>>(x, W1, h, N);
  k_agg<<<ablk, 256, 0, stream>>>(h, bufB, offs, dinv, b1, nullptr, h1, N, 0);
  // ---- layer 2 (reuse h buffer for h1 @ W2^T) ----
  k_gemm<HID><<<gblk, 256, 0, stream>>>(h1, W2, h, N);
  k_agg<<<ablk, 256, 0, stream>>>(h, bufB, offs, dinv, b2, h1, out, N, 1);
}

// Round 4
// 288.109 us; speedup vs baseline: 2.1047x; 1.1067x over previous
//
#include <hip/hip_runtime.h>

#define HID 64
#define DIN 128
#define NBLK 512                // blocks for hist/scatter passes

typedef unsigned long long ull;
typedef unsigned short u16;

static __device__ __forceinline__ u16 f2bf(float f) {
  // round-to-nearest-even bf16
  unsigned u = __float_as_uint(f);
  unsigned lsb = (u >> 16) & 1u;
  u += 0x7fffu + lsb;
  return (u16)(u >> 16);
}
static __device__ __forceinline__ float bf2f(u16 u) {
  return __uint_as_float(((unsigned)u) << 16);
}

// ============ build pass A: coarse histogram (bucket = dst>>8) ============

__global__ __launch_bounds__(256) void k_histA(const int* __restrict__ dst,
                                               int* __restrict__ G,
                                               int E, int NBC, int chunk) {
  __shared__ int h[256];
  int b = blockIdx.x, tid = threadIdx.x;
  h[tid] = 0;
  __syncthreads();
  int e0 = b * chunk, e1 = min(E, e0 + chunk);
  for (int e = e0 + tid; e < e1; e += 256) atomicAdd(&h[dst[e] >> 8], 1);
  __syncthreads();
  if (tid < NBC) G[tid * NBLK + b] = h[tid];   // bin-major for counting-sort scan
}

// ============ exclusive scan of G (L = NBC*NBLK elems), chunk=2048 ============

__global__ __launch_bounds__(256) void k_chunksum(const int* __restrict__ G, int* bsum, int L) {
  int b = blockIdx.x, t = threadIdx.x;
  int base = b * 2048;
  int s = 0;
  for (int i = t; i < 2048; i += 256) {
    int g = base + i;
    s += (g < L) ? G[g] : 0;
  }
  __shared__ int red[4];
  for (int o = 32; o > 0; o >>= 1) s += __shfl_down(s, o);
  if ((t & 63) == 0) red[t >> 6] = s;
  __syncthreads();
  if (t == 0) bsum[b] = red[0] + red[1] + red[2] + red[3];
}

__global__ __launch_bounds__(64) void k_scanbsum(int* bsum, int nb) {
  int lane = threadIdx.x;
  int v = (lane < nb) ? bsum[lane] : 0;
  int incl = v;
  for (int o = 1; o < 64; o <<= 1) {
    int u = __shfl_up(incl, o);
    if (lane >= o) incl += u;
  }
  if (lane < nb) bsum[lane] = incl - v;   // exclusive
}

__global__ __launch_bounds__(256) void k_scanfinal(int* G, const int* __restrict__ bsum, int L) {
  int b = blockIdx.x, t = threadIdx.x;
  int i0 = b * 2048 + t * 8;
  int v[8], tsum = 0;
#pragma unroll
  for (int k = 0; k < 8; ++k) {
    v[k] = (i0 + k < L) ? G[i0 + k] : 0;
    tsum += v[k];
  }
  int incl = tsum;
  for (int o = 1; o < 64; o <<= 1) {
    int u = __shfl_up(incl, o);
    if ((t & 63) >= o) incl += u;
  }
  int wexcl = incl - tsum;
  __shared__ int wtot[4];
  int w = t >> 6;
  if ((t & 63) == 63) wtot[w] = incl;
  __syncthreads();
  int wbase = 0;
  for (int i = 0; i < w; ++i) wbase += wtot[i];
  int run = bsum[b] + wbase + wexcl;
#pragma unroll
  for (int k = 0; k < 8; ++k) {
    if (i0 + k < L) G[i0 + k] = run;      // in-place: v[] already read
    run += v[k];
  }
}

// ============ pass A scatter: coarse-bucketed records, LDS cursors ============
// record int2 = ( float_bits(ew), (src<<16)|dst )

__global__ __launch_bounds__(256) void k_scatterA(const int* __restrict__ src,
                                                  const int* __restrict__ dst,
                                                  const float* __restrict__ ew,
                                                  const int* __restrict__ Gs,
                                                  int2* __restrict__ bufA,
                                                  int E, int NBC, int chunk) {
  __shared__ int cur[256];                 // NBC <= 256 (N <= 65536)
  int b = blockIdx.x, tid = threadIdx.x;
  if (tid < NBC) cur[tid] = Gs[tid * NBLK + b];   // this block's reserved run per bucket
  __syncthreads();
  int e0 = b * chunk, e1 = min(E, e0 + chunk);
  for (int e = e0 + tid; e < e1; e += 256) {
    int s = src[e], d = dst[e];
    float w = ew[e];
    int p = atomicAdd(&cur[d >> 8], 1);
    bufA[p] = make_int2(__float_as_int(w), (int)(((unsigned)s << 16) | (unsigned)d));
  }
}

// ============ pass B: one block per coarse bucket -> dst-grouped + offs + dinv ============

__global__ __launch_bounds__(256) void k_passB(const int2* __restrict__ bufA,
                                               const int* __restrict__ Gs,
                                               int2* __restrict__ bufB,
                                               int* __restrict__ offs,
                                               float* __restrict__ dinv,
                                               int NBC, int E, int N) {
  int bin = blockIdx.x, tid = threadIdx.x;
  __shared__ int h2[256];
  __shared__ int cur[256];
  __shared__ float dg[256];
  int base = Gs[bin * NBLK];
  int end  = (bin + 1 < NBC) ? Gs[(bin + 1) * NBLK] : E;
  int m = end - base;
  h2[tid] = 0;
  dg[tid] = 0.f;
  __syncthreads();
  // phase 1: fine histogram of dst&255
  for (int i = tid; i < m; i += 256) {
    unsigned sd = (unsigned)bufA[base + i].y;
    atomicAdd(&h2[sd & 255], 1);
  }
  __syncthreads();
  int own = h2[tid];
  // inclusive Hillis-Steele scan over 256 bins
  for (int o = 1; o < 256; o <<= 1) {
    int u = (tid >= o) ? h2[tid - o] : 0;
    __syncthreads();
    h2[tid] += u;
    __syncthreads();
  }
  int excl = h2[tid] - own;
  cur[tid] = excl;
  int nd = (bin << 8) + tid;
  if (nd < N) offs[nd] = base + excl;
  if (bin == NBC - 1 && tid == 0) offs[N] = E;
  __syncthreads();
  // phase 2: scatter into dst-grouped order + weighted degree
  for (int i = tid; i < m; i += 256) {
    int2 r = bufA[base + i];
    unsigned sd = (unsigned)r.y;
    int dl = (int)(sd & 255u);
    int p = atomicAdd(&cur[dl], 1);
    bufB[base + p] = r;
    atomicAdd(&dg[dl], __int_as_float(r.x));
  }
  __syncthreads();
  if (nd < N) dinv[nd] = rsqrtf(1.0f + dg[tid]);   // self-loop weight 1.0; deg>=1
}

// ============ GEMM: out[N][64] = X[N][K] @ W[64][K]^T, bf16 output ============

template <int K>
__global__ __launch_bounds__(256) void k_gemm(const float* __restrict__ X,
                                              const float* __restrict__ W,
                                              u16* __restrict__ out, int n_nodes) {
  constexpr int PAD = 68;
  __shared__ float WT[64 * PAD];          // WT[d][j]
  __shared__ float XT[64 * PAD];          // XT[d][m]
  const int tid = threadIdx.x;
  const int n0 = blockIdx.x * 64;
  const int tx = tid & 15;                // feature group: j = 4*tx + ji
  const int ty = tid >> 4;                // node group:    m = 4*ty + mi
  float acc[4][4] = {{0.f}};

  for (int ph = 0; ph < K / 64; ++ph) {
    __syncthreads();
    for (int idx = tid; idx < 64 * 64; idx += 256) {
      int j = idx >> 6, d = idx & 63;     // coalesced global reads (d fastest)
      WT[d * PAD + j] = W[j * K + ph * 64 + d];
      int n = n0 + j;
      XT[d * PAD + j] = (n < n_nodes) ? X[(size_t)n * K + ph * 64 + d] : 0.f;
    }
    __syncthreads();
#pragma unroll 4
    for (int d = 0; d < 64; ++d) {
      float4 wv = *reinterpret_cast<const float4*>(&WT[d * PAD + 4 * tx]);
      float4 xv = *reinterpret_cast<const float4*>(&XT[d * PAD + 4 * ty]);
      float xs[4] = {xv.x, xv.y, xv.z, xv.w};
      float ws[4] = {wv.x, wv.y, wv.z, wv.w};
#pragma unroll
      for (int mi = 0; mi < 4; ++mi)
#pragma unroll
        for (int ji = 0; ji < 4; ++ji)
          acc[mi][ji] = fmaf(xs[mi], ws[ji], acc[mi][ji]);
    }
  }

#pragma unroll
  for (int mi = 0; mi < 4; ++mi) {
    int n = n0 + 4 * ty + mi;
    if (n < n_nodes) {
      ushort4 o = make_ushort4(f2bf(acc[mi][0]), f2bf(acc[mi][1]),
                               f2bf(acc[mi][2]), f2bf(acc[mi][3]));
      *reinterpret_cast<ushort4*>(&out[(size_t)n * HID + 4 * tx]) = o;
    }
  }
}

// ============ aggregation: one wave per node, lane = feature ============
// h is bf16 (128 B/row gather). Batch: lane l loads edge record l (coalesced
// int2) + dinv[src], computes norm, shfl-broadcasts into lane=feature FMAs.
// mode 0: out = relu(agg + bias)          (layer 1 -> h1, fp32)
// mode 1: out = agg + bias + resid        (layer 2 -> final, fp32)

__global__ __launch_bounds__(256) void k_agg(const u16* __restrict__ h,
                                             const int2* __restrict__ recs,
                                             const int* __restrict__ offs,
                                             const float* __restrict__ dinv,
                                             const float* __restrict__ bias,
                                             const float* __restrict__ resid,
                                             float* __restrict__ out, int n_nodes, int mode) {
  int gw = (blockIdx.x * 256 + threadIdx.x) >> 6;  // node id
  int j = threadIdx.x & 63;                        // feature (= lane)
  if (gw >= n_nodes) return;
  int beg = offs[gw], end = offs[gw + 1];
  int m = end - beg;
  float di = dinv[gw];
  float acc  = bf2f(h[(size_t)gw * HID + j]) * (di * di);  // self loop (weight 1.0)
  float acc2 = 0.f, acc3 = 0.f, acc4 = 0.f;

  for (int b0 = 0; b0 < m; b0 += 64) {
    int l = b0 + j;                                // lane = edge index in batch
    int s = 0; float nrm = 0.f;
    if (l < m) {
      int2 r = recs[beg + l];
      s = (int)(((unsigned)r.y) >> 16);
      nrm = dinv[s] * __int_as_float(r.x) * di;
    }
    int lim = m - b0; if (lim > 64) lim = 64;
    int i = 0;
    for (; i + 4 <= lim; i += 4) {                 // 4 gathers in flight
      int s0 = __shfl(s, i);     float w0 = __shfl(nrm, i);
      int s1 = __shfl(s, i + 1); float w1 = __shfl(nrm, i + 1);
      int s2 = __shfl(s, i + 2); float w2 = __shfl(nrm, i + 2);
      int s3 = __shfl(s, i + 3); float w3 = __shfl(nrm, i + 3);
      u16 g0 = h[(size_t)s0 * HID + j];
      u16 g1 = h[(size_t)s1 * HID + j];
      u16 g2 = h[(size_t)s2 * HID + j];
      u16 g3 = h[(size_t)s3 * HID + j];
      acc  = fmaf(bf2f(g0), w0, acc);
      acc2 = fmaf(bf2f(g1), w1, acc2);
      acc3 = fmaf(bf2f(g2), w2, acc3);
      acc4 = fmaf(bf2f(g3), w3, acc4);
    }
    for (; i < lim; ++i) {
      int s0 = __shfl(s, i); float w0 = __shfl(nrm, i);
      acc = fmaf(bf2f(h[(size_t)s0 * HID + j]), w0, acc);
    }
  }
  acc += acc2 + acc3 + acc4 + bias[j];
  if (mode == 0) acc = fmaxf(acc, 0.f);
  else acc += resid[(size_t)gw * HID + j];
  out[(size_t)gw * HID + j] = acc;
}

// ============ launcher ============

extern "C" void kernel_launch(void* const* d_in, const int* in_sizes, int n_in,
                              void* d_out, int out_size, void* d_ws, size_t ws_size,
                              hipStream_t stream) {
  const float* x  = (const float*)d_in[0];
  const int*   ei = (const int*)d_in[1];
  const float* ew = (const float*)d_in[2];
  const float* W1 = (const float*)d_in[3];
  const float* b1 = (const float*)d_in[4];
  const float* W2 = (const float*)d_in[5];
  const float* b2 = (const float*)d_in[6];
  float* out = (float*)d_out;

  const int N = in_sizes[0] / DIN;
  const int E = in_sizes[2];
  const int* src = ei;        // ei shape (2,E) row-major
  const int* dst = ei + E;

  const int NBC = (N + 255) >> 8;          // coarse buckets (196 for N=50000)
  const int L = NBC * NBLK;                // G length
  const int chunk = (E + NBLK - 1) / NBLK;
  const int nch = (L + 2047) / 2048;       // scan chunks (<=64)

  char* p = (char*)d_ws;
  auto carve = [&](size_t bytes) {
    char* r = p;
    p += (bytes + 255) & ~(size_t)255;
    return r;
  };
  int*   G     = (int*)carve((size_t)L * 4);
  int*   bsum  = (int*)carve(64 * 4);
  int*   offs  = (int*)carve((size_t)(N + 1) * 4);
  float* dinv  = (float*)carve((size_t)N * 4);
  int2*  bufA  = (int2*)carve((size_t)E * 8);
  int2*  bufB  = (int2*)carve((size_t)E * 8);
  u16*   h     = (u16*)carve((size_t)N * HID * 2);   // bf16 linear outputs (gathered)
  float* h1    = (float*)carve((size_t)N * HID * 4); // fp32 layer-1 activations

  int gblk = (N + 63) / 64;
  int ablk = (N + 3) / 4;

  // ---- build (zero global atomics) ----
  k_histA<<<NBLK, 256, 0, stream>>>(dst, G, E, NBC, chunk);
  k_chunksum<<<nch, 256, 0, stream>>>(G, bsum, L);
  k_scanbsum<<<1, 64, 0, stream>>>(bsum, nch);
  k_scanfinal<<<nch, 256, 0, stream>>>(G, bsum, L);
  k_scatterA<<<NBLK, 256, 0, stream>>>(src, dst, ew, G, bufA, E, NBC, chunk);
  k_passB<<<NBC, 256, 0, stream>>>(bufA, G, bufB, offs, dinv, NBC, E, N);

  // ---- layer 1 ----
  k_gemm<DIN><<<gblk, 256, 0, stream>>>(x, W1, h, N);
  k_agg<<<ablk, 256, 0, stream>>>(h, bufB, offs, dinv, b1, nullptr, h1, N, 0);
  // ---- layer 2 (reuse h buffer for h1 @ W2^T) ----
  k_gemm<HID><<<gblk, 256, 0, stream>>>(h1, W2, h, N);
  k_agg<<<ablk, 256, 0, stream>>>(h, bufB, offs, dinv, b2, h1, out, N, 1);
}

// Round 5
// 273.101 us; speedup vs baseline: 2.2203x; 1.0550x over previous
//
#include <hip/hip_runtime.h>

#define HID 64
#define DIN 128
#define NBLK 512                // blocks for hist/scatter passes

typedef unsigned long long ull;
typedef unsigned short u16;

static __device__ __forceinline__ u16 f2bf(float f) {
  unsigned u = __float_as_uint(f);
  unsigned lsb = (u >> 16) & 1u;
  u += 0x7fffu + lsb;
  return (u16)(u >> 16);
}
static __device__ __forceinline__ float bf2f(u16 u) {
  return __uint_as_float(((unsigned)u) << 16);
}

// ============ build pass A: coarse histogram (bucket = dst>>8) ============

__global__ __launch_bounds__(512) void k_histA(const int* __restrict__ dst,
                                               int* __restrict__ G,
                                               int E, int NBC, int chunk) {
  __shared__ int h[256];
  int b = blockIdx.x, tid = threadIdx.x;
  if (tid < 256) h[tid] = 0;
  __syncthreads();
  int e0 = b * chunk, e1 = min(E, e0 + chunk);
  for (int e = e0 + tid; e < e1; e += 512) atomicAdd(&h[dst[e] >> 8], 1);
  __syncthreads();
  if (tid < NBC) G[tid * NBLK + b] = h[tid];   // bin-major for counting-sort scan
}

// ============ exclusive scan of G (L = NBC*NBLK elems), chunk=2048 ============

__global__ __launch_bounds__(256) void k_chunksum(const int* __restrict__ G, int* bsum, int L) {
  int b = blockIdx.x, t = threadIdx.x;
  int base = b * 2048;
  int s = 0;
  for (int i = t; i < 2048; i += 256) {
    int g = base + i;
    s += (g < L) ? G[g] : 0;
  }
  __shared__ int red[4];
  for (int o = 32; o > 0; o >>= 1) s += __shfl_down(s, o);
  if ((t & 63) == 0) red[t >> 6] = s;
  __syncthreads();
  if (t == 0) bsum[b] = red[0] + red[1] + red[2] + red[3];
}

__global__ __launch_bounds__(64) void k_scanbsum(int* bsum, int nb) {
  int lane = threadIdx.x;
  int v = (lane < nb) ? bsum[lane] : 0;
  int incl = v;
  for (int o = 1; o < 64; o <<= 1) {
    int u = __shfl_up(incl, o);
    if (lane >= o) incl += u;
  }
  if (lane < nb) bsum[lane] = incl - v;   // exclusive
}

__global__ __launch_bounds__(256) void k_scanfinal(int* G, const int* __restrict__ bsum, int L) {
  int b = blockIdx.x, t = threadIdx.x;
  int i0 = b * 2048 + t * 8;
  int v[8], tsum = 0;
#pragma unroll
  for (int k = 0; k < 8; ++k) {
    v[k] = (i0 + k < L) ? G[i0 + k] : 0;
    tsum += v[k];
  }
  int incl = tsum;
  for (int o = 1; o < 64; o <<= 1) {
    int u = __shfl_up(incl, o);
    if ((t & 63) >= o) incl += u;
  }
  int wexcl = incl - tsum;
  __shared__ int wtot[4];
  int w = t >> 6;
  if ((t & 63) == 63) wtot[w] = incl;
  __syncthreads();
  int wbase = 0;
  for (int i = 0; i < w; ++i) wbase += wtot[i];
  int run = bsum[b] + wbase + wexcl;
#pragma unroll
  for (int k = 0; k < 8; ++k) {
    if (i0 + k < L) G[i0 + k] = run;      // in-place: v[] already read
    run += v[k];
  }
}

// ============ pass A scatter: coarse-bucketed records, LDS cursors ============
// record int2 = ( float_bits(ew), (src<<16)|dst )

__global__ __launch_bounds__(512) void k_scatterA(const int* __restrict__ src,
                                                  const int* __restrict__ dst,
                                                  const float* __restrict__ ew,
                                                  const int* __restrict__ Gs,
                                                  int2* __restrict__ bufA,
                                                  int E, int NBC, int chunk) {
  __shared__ int cur[256];                 // NBC <= 256 (N <= 65536)
  int b = blockIdx.x, tid = threadIdx.x;
  if (tid < NBC) cur[tid] = Gs[tid * NBLK + b];   // this block's reserved run per bucket
  __syncthreads();
  int e0 = b * chunk, e1 = min(E, e0 + chunk);
  for (int e = e0 + tid; e < e1; e += 512) {
    int s = src[e], d = dst[e];
    float w = ew[e];
    int p = atomicAdd(&cur[d >> 8], 1);
    bufA[p] = make_int2(__float_as_int(w), (int)(((unsigned)s << 16) | (unsigned)d));
  }
}

// ============ pass B: one block per coarse bucket -> dst-grouped + offs + dinv ============

__global__ __launch_bounds__(512) void k_passB(const int2* __restrict__ bufA,
                                               const int* __restrict__ Gs,
                                               int2* __restrict__ bufB,
                                               int* __restrict__ offs,
                                               float* __restrict__ dinv,
                                               int NBC, int E, int N) {
  int bin = blockIdx.x, tid = threadIdx.x;
  __shared__ int h2[256];
  __shared__ int cur[256];
  __shared__ float dg[256];
  int base = Gs[bin * NBLK];
  int end  = (bin + 1 < NBC) ? Gs[(bin + 1) * NBLK] : E;
  int m = end - base;
  if (tid < 256) { h2[tid] = 0; dg[tid] = 0.f; }
  __syncthreads();
  // phase 1: fine histogram of dst&255
  for (int i = tid; i < m; i += 512) {
    unsigned sd = (unsigned)bufA[base + i].y;
    atomicAdd(&h2[sd & 255], 1);
  }
  __syncthreads();
  int own = (tid < 256) ? h2[tid] : 0;
  // inclusive Hillis-Steele scan over 256 bins
  for (int o = 1; o < 256; o <<= 1) {
    int u = 0;
    if (tid < 256 && tid >= o) u = h2[tid - o];
    __syncthreads();
    if (tid < 256) h2[tid] += u;
    __syncthreads();
  }
  int nd = (bin << 8) + tid;
  if (tid < 256) {
    int excl = h2[tid] - own;
    cur[tid] = excl;
    if (nd < N) offs[nd] = base + excl;
  }
  if (bin == NBC - 1 && tid == 0) offs[N] = E;
  __syncthreads();
  // phase 2: scatter into dst-grouped order + weighted degree
  for (int i = tid; i < m; i += 512) {
    int2 r = bufA[base + i];
    unsigned sd = (unsigned)r.y;
    int dl = (int)(sd & 255u);
    int p = atomicAdd(&cur[dl], 1);
    bufB[base + p] = r;
    atomicAdd(&dg[dl], __int_as_float(r.x));
  }
  __syncthreads();
  if (tid < 256 && nd < N) dinv[nd] = rsqrtf(1.0f + dg[tid]);  // self-loop w=1; deg>=1
}

// ============ norm prepass: record (ew, src|dst) -> (norm, src) ============

__global__ __launch_bounds__(256) void k_norm(int2* __restrict__ recs,
                                              const float* __restrict__ dinv, int E) {
  int e = blockIdx.x * 256 + threadIdx.x;
  if (e < E) {
    int2 r = recs[e];
    unsigned sd = (unsigned)r.y;
    int s = (int)(sd >> 16), d = (int)(sd & 0xffffu);
    float nrm = dinv[s] * __int_as_float(r.x) * dinv[d];
    recs[e] = make_int2(__float_as_int(nrm), s);
  }
}

// ============ GEMM: out[N][64] = X[N][K] @ W[64][K]^T, bf16 output ============

template <int K>
__global__ __launch_bounds__(256) void k_gemm(const float* __restrict__ X,
                                              const float* __restrict__ W,
                                              u16* __restrict__ out, int n_nodes) {
  constexpr int PAD = 68;
  __shared__ float WT[64 * PAD];          // WT[d][j]
  __shared__ float XT[64 * PAD];          // XT[d][m]
  const int tid = threadIdx.x;
  const int n0 = blockIdx.x * 64;
  const int tx = tid & 15;                // feature group: j = 4*tx + ji
  const int ty = tid >> 4;                // node group:    m = 4*ty + mi
  float acc[4][4] = {{0.f}};

  for (int ph = 0; ph < K / 64; ++ph) {
    __syncthreads();
    for (int idx = tid; idx < 64 * 64; idx += 256) {
      int j = idx >> 6, d = idx & 63;     // coalesced global reads (d fastest)
      WT[d * PAD + j] = W[j * K + ph * 64 + d];
      int n = n0 + j;
      XT[d * PAD + j] = (n < n_nodes) ? X[(size_t)n * K + ph * 64 + d] : 0.f;
    }
    __syncthreads();
#pragma unroll 4
    for (int d = 0; d < 64; ++d) {
      float4 wv = *reinterpret_cast<const float4*>(&WT[d * PAD + 4 * tx]);
      float4 xv = *reinterpret_cast<const float4*>(&XT[d * PAD + 4 * ty]);
      float xs[4] = {xv.x, xv.y, xv.z, xv.w};
      float ws[4] = {wv.x, wv.y, wv.z, wv.w};
#pragma unroll
      for (int mi = 0; mi < 4; ++mi)
#pragma unroll
        for (int ji = 0; ji < 4; ++ji)
          acc[mi][ji] = fmaf(xs[mi], ws[ji], acc[mi][ji]);
    }
  }

#pragma unroll
  for (int mi = 0; mi < 4; ++mi) {
    int n = n0 + 4 * ty + mi;
    if (n < n_nodes) {
      ushort4 o = make_ushort4(f2bf(acc[mi][0]), f2bf(acc[mi][1]),
                               f2bf(acc[mi][2]), f2bf(acc[mi][3]));
      *reinterpret_cast<ushort4*>(&out[(size_t)n * HID + 4 * tx]) = o;
    }
  }
}

// ============ aggregation: one wave per node, lane = feature ============
// Records are (norm, src); node id + record stream forced wave-uniform via
// readfirstlane so record loads become s_load and gathers use scalar bases.
// Zero LDS-pipe ops in the hot loop; 8 gathers in flight.
// mode 0: out = relu(agg + bias)          (layer 1 -> h1, fp32)
// mode 1: out = agg + bias + resid        (layer 2 -> final, fp32)

__global__ __launch_bounds__(256) void k_agg(const u16* __restrict__ h,
                                             const int2* __restrict__ recs,
                                             const int* __restrict__ offs,
                                             const float* __restrict__ dinv,
                                             const float* __restrict__ bias,
                                             const float* __restrict__ resid,
                                             float* __restrict__ out, int n_nodes, int mode) {
  int gw = __builtin_amdgcn_readfirstlane((int)((blockIdx.x * 256 + threadIdx.x) >> 6));
  int j = threadIdx.x & 63;                        // feature (= lane)
  if (gw >= n_nodes) return;
  int beg = __builtin_amdgcn_readfirstlane(offs[gw]);
  int end = __builtin_amdgcn_readfirstlane(offs[gw + 1]);
  float di = dinv[gw];
  float a0 = bf2f(h[(size_t)gw * HID + j]) * (di * di);  // self loop (weight 1.0)
  float a1 = 0.f, a2 = 0.f, a3 = 0.f, a4 = 0.f, a5 = 0.f, a6 = 0.f, a7 = 0.f;

  int i = beg;
  for (; i + 8 <= end; i += 8) {
    int2 r0 = recs[i];     int2 r1 = recs[i + 1];
    int2 r2 = recs[i + 2]; int2 r3 = recs[i + 3];
    int2 r4 = recs[i + 4]; int2 r5 = recs[i + 5];
    int2 r6 = recs[i + 6]; int2 r7 = recs[i + 7];
    u16 g0 = h[(size_t)r0.y * HID + j];
    u16 g1 = h[(size_t)r1.y * HID + j];
    u16 g2 = h[(size_t)r2.y * HID + j];
    u16 g3 = h[(size_t)r3.y * HID + j];
    u16 g4 = h[(size_t)r4.y * HID + j];
    u16 g5 = h[(size_t)r5.y * HID + j];
    u16 g6 = h[(size_t)r6.y * HID + j];
    u16 g7 = h[(size_t)r7.y * HID + j];
    a0 = fmaf(bf2f(g0), __int_as_float(r0.x), a0);
    a1 = fmaf(bf2f(g1), __int_as_float(r1.x), a1);
    a2 = fmaf(bf2f(g2), __int_as_float(r2.x), a2);
    a3 = fmaf(bf2f(g3), __int_as_float(r3.x), a3);
    a4 = fmaf(bf2f(g4), __int_as_float(r4.x), a4);
    a5 = fmaf(bf2f(g5), __int_as_float(r5.x), a5);
    a6 = fmaf(bf2f(g6), __int_as_float(r6.x), a6);
    a7 = fmaf(bf2f(g7), __int_as_float(r7.x), a7);
  }
  for (; i < end; ++i) {
    int2 r = recs[i];
    a0 = fmaf(bf2f(h[(size_t)r.y * HID + j]), __int_as_float(r.x), a0);
  }
  float acc = ((a0 + a1) + (a2 + a3)) + ((a4 + a5) + (a6 + a7)) + bias[j];
  if (mode == 0) acc = fmaxf(acc, 0.f);
  else acc += resid[(size_t)gw * HID + j];
  out[(size_t)gw * HID + j] = acc;
}

// ============ launcher ============

extern "C" void kernel_launch(void* const* d_in, const int* in_sizes, int n_in,
                              void* d_out, int out_size, void* d_ws, size_t ws_size,
                              hipStream_t stream) {
  const float* x  = (const float*)d_in[0];
  const int*   ei = (const int*)d_in[1];
  const float* ew = (const float*)d_in[2];
  const float* W1 = (const float*)d_in[3];
  const float* b1 = (const float*)d_in[4];
  const float* W2 = (const float*)d_in[5];
  const float* b2 = (const float*)d_in[6];
  float* out = (float*)d_out;

  const int N = in_sizes[0] / DIN;
  const int E = in_sizes[2];
  const int* src = ei;        // ei shape (2,E) row-major
  const int* dst = ei + E;

  const int NBC = (N + 255) >> 8;          // coarse buckets (196 for N=50000)
  const int L = NBC * NBLK;                // G length
  const int chunk = (E + NBLK - 1) / NBLK;
  const int nch = (L + 2047) / 2048;       // scan chunks (<=64)

  char* p = (char*)d_ws;
  auto carve = [&](size_t bytes) {
    char* r = p;
    p += (bytes + 255) & ~(size_t)255;
    return r;
  };
  int*   G     = (int*)carve((size_t)L * 4);
  int*   bsum  = (int*)carve(64 * 4);
  int*   offs  = (int*)carve((size_t)(N + 1) * 4);
  float* dinv  = (float*)carve((size_t)N * 4);
  int2*  bufA  = (int2*)carve((size_t)E * 8);
  int2*  bufB  = (int2*)carve((size_t)E * 8);
  u16*   h     = (u16*)carve((size_t)N * HID * 2);   // bf16 linear outputs (gathered)
  float* h1    = (float*)carve((size_t)N * HID * 4); // fp32 layer-1 activations

  int gblk = (N + 63) / 64;
  int ablk = (N + 3) / 4;

  // ---- build (zero global atomics) ----
  k_histA<<<NBLK, 512, 0, stream>>>(dst, G, E, NBC, chunk);
  k_chunksum<<<nch, 256, 0, stream>>>(G, bsum, L);
  k_scanbsum<<<1, 64, 0, stream>>>(bsum, nch);
  k_scanfinal<<<nch, 256, 0, stream>>>(G, bsum, L);
  k_scatterA<<<NBLK, 512, 0, stream>>>(src, dst, ew, G, bufA, E, NBC, chunk);
  k_passB<<<NBC, 512, 0, stream>>>(bufA, G, bufB, offs, dinv, NBC, E, N);
  k_norm<<<(E + 255) / 256, 256, 0, stream>>>(bufB, dinv, E);

  // ---- layer 1 ----
  k_gemm<DIN><<<gblk, 256, 0, stream>>>(x, W1, h, N);
  k_agg<<<ablk, 256, 0, stream>>>(h, bufB, offs, dinv, b1, nullptr, h1, N, 0);
  // ---- layer 2 (reuse h buffer for h1 @ W2^T) ----
  k_gemm<HID><<<gblk, 256, 0, stream>>>(h1, W2, h, N);
  k_agg<<<ablk, 256, 0, stream>>>(h, bufB, offs, dinv, b2, h1, out, N, 1);
}

// Round 6
// 265.280 us; speedup vs baseline: 2.2858x; 1.0295x over previous
//
#include <hip/hip_runtime.h>

#define HID 64
#define DIN 128
#define NBLK 512                // blocks for hist/scatter passes

typedef unsigned long long ull;
typedef unsigned short u16;

static __device__ __forceinline__ u16 f2bf(float f) {
  unsigned u = __float_as_uint(f);
  unsigned lsb = (u >> 16) & 1u;
  u += 0x7fffu + lsb;
  return (u16)(u >> 16);
}

// ============ build pass A: coarse histogram (bucket = dst>>8) ============

__global__ __launch_bounds__(512) void k_histA(const int* __restrict__ dst,
                                               int* __restrict__ G,
                                               int E, int NBC, int chunk) {
  __shared__ int h[256];
  int b = blockIdx.x, tid = threadIdx.x;
  if (tid < 256) h[tid] = 0;
  __syncthreads();
  int e0 = b * chunk, e1 = min(E, e0 + chunk);
  for (int e = e0 + tid; e < e1; e += 512) atomicAdd(&h[dst[e] >> 8], 1);
  __syncthreads();
  if (tid < NBC) G[tid * NBLK + b] = h[tid];   // bin-major for counting-sort scan
}

// ============ exclusive scan of G (L = NBC*NBLK elems), chunk=2048 ============

__global__ __launch_bounds__(256) void k_chunksum(const int* __restrict__ G, int* bsum, int L) {
  int b = blockIdx.x, t = threadIdx.x;
  int base = b * 2048;
  int s = 0;
  for (int i = t; i < 2048; i += 256) {
    int g = base + i;
    s += (g < L) ? G[g] : 0;
  }
  __shared__ int red[4];
  for (int o = 32; o > 0; o >>= 1) s += __shfl_down(s, o);
  if ((t & 63) == 0) red[t >> 6] = s;
  __syncthreads();
  if (t == 0) bsum[b] = red[0] + red[1] + red[2] + red[3];
}

__global__ __launch_bounds__(64) void k_scanbsum(int* bsum, int nb) {
  int lane = threadIdx.x;
  int v = (lane < nb) ? bsum[lane] : 0;
  int incl = v;
  for (int o = 1; o < 64; o <<= 1) {
    int u = __shfl_up(incl, o);
    if (lane >= o) incl += u;
  }
  if (lane < nb) bsum[lane] = incl - v;   // exclusive
}

__global__ __launch_bounds__(256) void k_scanfinal(int* G, const int* __restrict__ bsum, int L) {
  int b = blockIdx.x, t = threadIdx.x;
  int i0 = b * 2048 + t * 8;
  int v[8], tsum = 0;
#pragma unroll
  for (int k = 0; k < 8; ++k) {
    v[k] = (i0 + k < L) ? G[i0 + k] : 0;
    tsum += v[k];
  }
  int incl = tsum;
  for (int o = 1; o < 64; o <<= 1) {
    int u = __shfl_up(incl, o);
    if ((t & 63) >= o) incl += u;
  }
  int wexcl = incl - tsum;
  __shared__ int wtot[4];
  int w = t >> 6;
  if ((t & 63) == 63) wtot[w] = incl;
  __syncthreads();
  int wbase = 0;
  for (int i = 0; i < w; ++i) wbase += wtot[i];
  int run = bsum[b] + wbase + wexcl;
#pragma unroll
  for (int k = 0; k < 8; ++k) {
    if (i0 + k < L) G[i0 + k] = run;      // in-place: v[] already read
    run += v[k];
  }
}

// ============ pass A scatter: coarse-bucketed records, LDS cursors ============
// record int2 = ( float_bits(ew), (src<<16)|dst )

__global__ __launch_bounds__(512) void k_scatterA(const int* __restrict__ src,
                                                  const int* __restrict__ dst,
                                                  const float* __restrict__ ew,
                                                  const int* __restrict__ Gs,
                                                  int2* __restrict__ bufA,
                                                  int E, int NBC, int chunk) {
  __shared__ int cur[256];                 // NBC <= 256 (N <= 65536)
  int b = blockIdx.x, tid = threadIdx.x;
  if (tid < NBC) cur[tid] = Gs[tid * NBLK + b];   // this block's reserved run per bucket
  __syncthreads();
  int e0 = b * chunk, e1 = min(E, e0 + chunk);
  for (int e = e0 + tid; e < e1; e += 512) {
    int s = src[e], d = dst[e];
    float w = ew[e];
    int p = atomicAdd(&cur[d >> 8], 1);
    bufA[p] = make_int2(__float_as_int(w), (int)(((unsigned)s << 16) | (unsigned)d));
  }
}

// ============ pass B: one block per coarse bucket -> dst-grouped + offs + dinv ============

__global__ __launch_bounds__(512) void k_passB(const int2* __restrict__ bufA,
                                               const int* __restrict__ Gs,
                                               int2* __restrict__ bufB,
                                               int* __restrict__ offs,
                                               float* __restrict__ dinv,
                                               int NBC, int E, int N) {
  int bin = blockIdx.x, tid = threadIdx.x;
  __shared__ int h2[256];
  __shared__ int cur[256];
  __shared__ float dg[256];
  int base = Gs[bin * NBLK];
  int end  = (bin + 1 < NBC) ? Gs[(bin + 1) * NBLK] : E;
  int m = end - base;
  if (tid < 256) { h2[tid] = 0; dg[tid] = 0.f; }
  __syncthreads();
  // phase 1: fine histogram of dst&255
  for (int i = tid; i < m; i += 512) {
    unsigned sd = (unsigned)bufA[base + i].y;
    atomicAdd(&h2[sd & 255], 1);
  }
  __syncthreads();
  int own = (tid < 256) ? h2[tid] : 0;
  // inclusive Hillis-Steele scan over 256 bins
  for (int o = 1; o < 256; o <<= 1) {
    int u = 0;
    if (tid < 256 && tid >= o) u = h2[tid - o];
    __syncthreads();
    if (tid < 256) h2[tid] += u;
    __syncthreads();
  }
  int nd = (bin << 8) + tid;
  if (tid < 256) {
    int excl = h2[tid] - own;
    cur[tid] = excl;
    if (nd < N) offs[nd] = base + excl;
  }
  if (bin == NBC - 1 && tid == 0) offs[N] = E;
  __syncthreads();
  // phase 2: scatter into dst-grouped order + weighted degree
  for (int i = tid; i < m; i += 512) {
    int2 r = bufA[base + i];
    unsigned sd = (unsigned)r.y;
    int dl = (int)(sd & 255u);
    int p = atomicAdd(&cur[dl], 1);
    bufB[base + p] = r;
    atomicAdd(&dg[dl], __int_as_float(r.x));
  }
  __syncthreads();
  if (tid < 256 && nd < N) dinv[nd] = rsqrtf(1.0f + dg[tid]);  // self-loop w=1; deg>=1
}

// ============ norm prepass: record (ew, src|dst) -> (norm, src) ============

__global__ __launch_bounds__(256) void k_norm(int2* __restrict__ recs,
                                              const float* __restrict__ dinv, int E) {
  int e = blockIdx.x * 256 + threadIdx.x;
  if (e < E) {
    int2 r = recs[e];
    unsigned sd = (unsigned)r.y;
    int s = (int)(sd >> 16), d = (int)(sd & 0xffffu);
    float nrm = dinv[s] * __int_as_float(r.x) * dinv[d];
    recs[e] = make_int2(__float_as_int(nrm), s);
  }
}

// ============ GEMM: out[N][64] = X[N][K] @ W[64][K]^T, bf16 output ============

template <int K>
__global__ __launch_bounds__(256) void k_gemm(const float* __restrict__ X,
                                              const float* __restrict__ W,
                                              u16* __restrict__ out, int n_nodes) {
  constexpr int PAD = 68;
  __shared__ float WT[64 * PAD];          // WT[d][j]
  __shared__ float XT[64 * PAD];          // XT[d][m]
  const int tid = threadIdx.x;
  const int n0 = blockIdx.x * 64;
  const int tx = tid & 15;                // feature group: j = 4*tx + ji
  const int ty = tid >> 4;                // node group:    m = 4*ty + mi
  float acc[4][4] = {{0.f}};

  for (int ph = 0; ph < K / 64; ++ph) {
    __syncthreads();
    for (int idx = tid; idx < 64 * 64; idx += 256) {
      int j = idx >> 6, d = idx & 63;     // coalesced global reads (d fastest)
      WT[d * PAD + j] = W[j * K + ph * 64 + d];
      int n = n0 + j;
      XT[d * PAD + j] = (n < n_nodes) ? X[(size_t)n * K + ph * 64 + d] : 0.f;
    }
    __syncthreads();
#pragma unroll 4
    for (int d = 0; d < 64; ++d) {
      float4 wv = *reinterpret_cast<const float4*>(&WT[d * PAD + 4 * tx]);
      float4 xv = *reinterpret_cast<const float4*>(&XT[d * PAD + 4 * ty]);
      float xs[4] = {xv.x, xv.y, xv.z, xv.w};
      float ws[4] = {wv.x, wv.y, wv.z, wv.w};
#pragma unroll
      for (int mi = 0; mi < 4; ++mi)
#pragma unroll
        for (int ji = 0; ji < 4; ++ji)
          acc[mi][ji] = fmaf(xs[mi], ws[ji], acc[mi][ji]);
    }
  }

#pragma unroll
  for (int mi = 0; mi < 4; ++mi) {
    int n = n0 + 4 * ty + mi;
    if (n < n_nodes) {
      ushort4 o = make_ushort4(f2bf(acc[mi][0]), f2bf(acc[mi][1]),
                               f2bf(acc[mi][2]), f2bf(acc[mi][3]));
      *reinterpret_cast<ushort4*>(&out[(size_t)n * HID + 4 * tx]) = o;
    }
  }
}

// ============ aggregation v2: one wave per node, 4 edges per wave-instruction ============
// Wave = 4 groups x 16 lanes. Group g handles edge i+g; lane covers 4 features
// via one 8B (4x bf16) load. One gather instruction = 4 src rows (512 B).
// Records loaded per-lane (recs[i+g], 16-lane dedup) -> norm/src land in the
// right lanes with no shuffles/selects. Epilogue: shfl_xor(16,32) group-reduce,
// lanes 0-15 write float4.
// mode 0: out = relu(agg + bias)          (layer 1 -> h1, fp32)
// mode 1: out = agg + bias + resid        (layer 2 -> final, fp32)

__device__ __forceinline__ void agg4(const u16* __restrict__ h,
                                     const int2* __restrict__ recs,
                                     int i, int g, int p4,
                                     float& a0, float& a1, float& a2, float& a3) {
  int2 r = recs[i + g];
  float w = __int_as_float(r.x);
  uint2 v = *reinterpret_cast<const uint2*>(&h[(size_t)r.y * HID + p4]);
  a0 = fmaf(__uint_as_float(v.x << 16), w, a0);
  a1 = fmaf(__uint_as_float(v.x & 0xffff0000u), w, a1);
  a2 = fmaf(__uint_as_float(v.y << 16), w, a2);
  a3 = fmaf(__uint_as_float(v.y & 0xffff0000u), w, a3);
}

__global__ __launch_bounds__(256) void k_agg(const u16* __restrict__ h,
                                             const int2* __restrict__ recs,
                                             const int* __restrict__ offs,
                                             const float* __restrict__ dinv,
                                             const float* __restrict__ bias,
                                             const float* __restrict__ resid,
                                             float* __restrict__ out, int n_nodes, int mode) {
  int gw = __builtin_amdgcn_readfirstlane((int)((blockIdx.x * 256 + threadIdx.x) >> 6));
  if (gw >= n_nodes) return;
  int lane = threadIdx.x & 63;
  int g = lane >> 4;                  // edge group 0..3
  int p4 = (lane & 15) * 4;           // feature base (4 features per lane)
  int beg = __builtin_amdgcn_readfirstlane(offs[gw]);
  int end = __builtin_amdgcn_readfirstlane(offs[gw + 1]);
  float di = dinv[gw];

  float a0 = 0.f, a1 = 0.f, a2 = 0.f, a3 = 0.f;
  float b0 = 0.f, b1 = 0.f, b2 = 0.f, b3 = 0.f;

  // self loop (weight di*di, counted once via group 0)
  {
    uint2 v = *reinterpret_cast<const uint2*>(&h[(size_t)gw * HID + p4]);
    float w = (g == 0) ? di * di : 0.f;
    a0 = fmaf(__uint_as_float(v.x << 16), w, a0);
    a1 = fmaf(__uint_as_float(v.x & 0xffff0000u), w, a1);
    a2 = fmaf(__uint_as_float(v.y << 16), w, a2);
    a3 = fmaf(__uint_as_float(v.y & 0xffff0000u), w, a3);
  }

  int i = beg;
  for (; i + 8 <= end; i += 8) {
    agg4(h, recs, i,     g, p4, a0, a1, a2, a3);
    agg4(h, recs, i + 4, g, p4, b0, b1, b2, b3);
  }
  if (i + 4 <= end) {
    agg4(h, recs, i, g, p4, a0, a1, a2, a3);
    i += 4;
  }
  if (i < end) {                       // masked tail, rem in 1..3
    int rem = end - i;
    int idx = i + ((g < rem) ? g : (rem - 1));
    int2 r = recs[idx];
    float w = (g < rem) ? __int_as_float(r.x) : 0.f;
    uint2 v = *reinterpret_cast<const uint2*>(&h[(size_t)r.y * HID + p4]);
    b0 = fmaf(__uint_as_float(v.x << 16), w, b0);
    b1 = fmaf(__uint_as_float(v.x & 0xffff0000u), w, b1);
    b2 = fmaf(__uint_as_float(v.y << 16), w, b2);
    b3 = fmaf(__uint_as_float(v.y & 0xffff0000u), w, b3);
  }

  float r0 = a0 + b0, r1 = a1 + b1, r2 = a2 + b2, r3 = a3 + b3;
  // reduce the 4 groups (lanes p, 16+p, 32+p, 48+p)
  r0 += __shfl_xor(r0, 16); r0 += __shfl_xor(r0, 32);
  r1 += __shfl_xor(r1, 16); r1 += __shfl_xor(r1, 32);
  r2 += __shfl_xor(r2, 16); r2 += __shfl_xor(r2, 32);
  r3 += __shfl_xor(r3, 16); r3 += __shfl_xor(r3, 32);

  if (g == 0) {
    float4 bb = *reinterpret_cast<const float4*>(&bias[p4]);
    r0 += bb.x; r1 += bb.y; r2 += bb.z; r3 += bb.w;
    if (mode == 0) {
      r0 = fmaxf(r0, 0.f); r1 = fmaxf(r1, 0.f);
      r2 = fmaxf(r2, 0.f); r3 = fmaxf(r3, 0.f);
    } else {
      float4 rs = *reinterpret_cast<const float4*>(&resid[(size_t)gw * HID + p4]);
      r0 += rs.x; r1 += rs.y; r2 += rs.z; r3 += rs.w;
    }
    *reinterpret_cast<float4*>(&out[(size_t)gw * HID + p4]) = make_float4(r0, r1, r2, r3);
  }
}

// ============ launcher ============

extern "C" void kernel_launch(void* const* d_in, const int* in_sizes, int n_in,
                              void* d_out, int out_size, void* d_ws, size_t ws_size,
                              hipStream_t stream) {
  const float* x  = (const float*)d_in[0];
  const int*   ei = (const int*)d_in[1];
  const float* ew = (const float*)d_in[2];
  const float* W1 = (const float*)d_in[3];
  const float* b1 = (const float*)d_in[4];
  const float* W2 = (const float*)d_in[5];
  const float* b2 = (const float*)d_in[6];
  float* out = (float*)d_out;

  const int N = in_sizes[0] / DIN;
  const int E = in_sizes[2];
  const int* src = ei;        // ei shape (2,E) row-major
  const int* dst = ei + E;

  const int NBC = (N + 255) >> 8;          // coarse buckets (196 for N=50000)
  const int L = NBC * NBLK;                // G length
  const int chunk = (E + NBLK - 1) / NBLK;
  const int nch = (L + 2047) / 2048;       // scan chunks (<=64)

  char* p = (char*)d_ws;
  auto carve = [&](size_t bytes) {
    char* r = p;
    p += (bytes + 255) & ~(size_t)255;
    return r;
  };
  int*   G     = (int*)carve((size_t)L * 4);
  int*   bsum  = (int*)carve(64 * 4);
  int*   offs  = (int*)carve((size_t)(N + 1) * 4);
  float* dinv  = (float*)carve((size_t)N * 4);
  int2*  bufA  = (int2*)carve((size_t)E * 8);
  int2*  bufB  = (int2*)carve((size_t)E * 8);
  u16*   h     = (u16*)carve((size_t)N * HID * 2);   // bf16 linear outputs (gathered)
  float* h1    = (float*)carve((size_t)N * HID * 4); // fp32 layer-1 activations

  int gblk = (N + 63) / 64;
  int ablk = (N + 3) / 4;

  // ---- build (zero global atomics) ----
  k_histA<<<NBLK, 512, 0, stream>>>(dst, G, E, NBC, chunk);
  k_chunksum<<<nch, 256, 0, stream>>>(G, bsum, L);
  k_scanbsum<<<1, 64, 0, stream>>>(bsum, nch);
  k_scanfinal<<<nch, 256, 0, stream>>>(G, bsum, L);
  k_scatterA<<<NBLK, 512, 0, stream>>>(src, dst, ew, G, bufA, E, NBC, chunk);
  k_passB<<<NBC, 512, 0, stream>>>(bufA, G, bufB, offs, dinv, NBC, E, N);
  k_norm<<<(E + 255) / 256, 256, 0, stream>>>(bufB, dinv, E);

  // ---- layer 1 ----
  k_gemm<DIN><<<gblk, 256, 0, stream>>>(x, W1, h, N);
  k_agg<<<ablk, 256, 0, stream>>>(h, bufB, offs, dinv, b1, nullptr, h1, N, 0);
  // ---- layer 2 (reuse h buffer for h1 @ W2^T) ----
  k_gemm<HID><<<gblk, 256, 0, stream>>>(h1, W2, h, N);
  k_agg<<<ablk, 256, 0, stream>>>(h, bufB, offs, dinv, b2, h1, out, N, 1);
}

// Round 7
// 244.564 us; speedup vs baseline: 2.4794x; 1.0847x over previous
//
#include <hip/hip_runtime.h>

#define HID 64
#define DIN 128
#define NBLK 512                // blocks for hist/scatter passes

typedef unsigned long long ull;
typedef unsigned short u16;

static __device__ __forceinline__ u16 f2bf(float f) {
  unsigned u = __float_as_uint(f);
  unsigned lsb = (u >> 16) & 1u;
  u += 0x7fffu + lsb;
  return (u16)(u >> 16);
}

// ============ build pass A: coarse histogram (bucket = dst>>8) ============

__global__ __launch_bounds__(512) void k_histA(const int* __restrict__ dst,
                                               int* __restrict__ G,
                                               int E, int NBC, int chunk) {
  __shared__ int h[256];
  int b = blockIdx.x, tid = threadIdx.x;
  if (tid < 256) h[tid] = 0;
  __syncthreads();
  int e0 = b * chunk, e1 = min(E, e0 + chunk);
  for (int e = e0 + tid; e < e1; e += 512) atomicAdd(&h[dst[e] >> 8], 1);
  __syncthreads();
  if (tid < NBC) G[tid * NBLK + b] = h[tid];   // bin-major for counting-sort scan
}

// ============ exclusive scan of G (L = NBC*NBLK elems), chunk=2048 ============

__global__ __launch_bounds__(256) void k_chunksum(const int* __restrict__ G, int* bsum, int L) {
  int b = blockIdx.x, t = threadIdx.x;
  int base = b * 2048;
  int s = 0;
  for (int i = t; i < 2048; i += 256) {
    int g = base + i;
    s += (g < L) ? G[g] : 0;
  }
  __shared__ int red[4];
  for (int o = 32; o > 0; o >>= 1) s += __shfl_down(s, o);
  if ((t & 63) == 0) red[t >> 6] = s;
  __syncthreads();
  if (t == 0) bsum[b] = red[0] + red[1] + red[2] + red[3];
}

__global__ __launch_bounds__(64) void k_scanbsum(int* bsum, int nb) {
  int lane = threadIdx.x;
  int v = (lane < nb) ? bsum[lane] : 0;
  int incl = v;
  for (int o = 1; o < 64; o <<= 1) {
    int u = __shfl_up(incl, o);
    if (lane >= o) incl += u;
  }
  if (lane < nb) bsum[lane] = incl - v;   // exclusive
}

__global__ __launch_bounds__(256) void k_scanfinal(int* G, const int* __restrict__ bsum, int L) {
  int b = blockIdx.x, t = threadIdx.x;
  int i0 = b * 2048 + t * 8;
  int v[8], tsum = 0;
#pragma unroll
  for (int k = 0; k < 8; ++k) {
    v[k] = (i0 + k < L) ? G[i0 + k] : 0;
    tsum += v[k];
  }
  int incl = tsum;
  for (int o = 1; o < 64; o <<= 1) {
    int u = __shfl_up(incl, o);
    if ((t & 63) >= o) incl += u;
  }
  int wexcl = incl - tsum;
  __shared__ int wtot[4];
  int w = t >> 6;
  if ((t & 63) == 63) wtot[w] = incl;
  __syncthreads();
  int wbase = 0;
  for (int i = 0; i < w; ++i) wbase += wtot[i];
  int run = bsum[b] + wbase + wexcl;
#pragma unroll
  for (int k = 0; k < 8; ++k) {
    if (i0 + k < L) G[i0 + k] = run;      // in-place: v[] already read
    run += v[k];
  }
}

// ============ pass A scatter: coarse-bucketed records, LDS cursors ============
// record int2 = ( float_bits(ew), (src<<16)|dst )

__global__ __launch_bounds__(512) void k_scatterA(const int* __restrict__ src,
                                                  const int* __restrict__ dst,
                                                  const float* __restrict__ ew,
                                                  const int* __restrict__ Gs,
                                                  int2* __restrict__ bufA,
                                                  int E, int NBC, int chunk) {
  __shared__ int cur[256];                 // NBC <= 256 (N <= 65536)
  int b = blockIdx.x, tid = threadIdx.x;
  if (tid < NBC) cur[tid] = Gs[tid * NBLK + b];   // this block's reserved run per bucket
  __syncthreads();
  int e0 = b * chunk, e1 = min(E, e0 + chunk);
  for (int e = e0 + tid; e < e1; e += 512) {
    int s = src[e], d = dst[e];
    float w = ew[e];
    int p = atomicAdd(&cur[d >> 8], 1);
    bufA[p] = make_int2(__float_as_int(w), (int)(((unsigned)s << 16) | (unsigned)d));
  }
}

// ============ pass B: one block per coarse bucket -> dst-grouped + offs + dinv ============

__global__ __launch_bounds__(512) void k_passB(const int2* __restrict__ bufA,
                                               const int* __restrict__ Gs,
                                               int2* __restrict__ bufB,
                                               int* __restrict__ offs,
                                               float* __restrict__ dinv,
                                               int NBC, int E, int N) {
  int bin = blockIdx.x, tid = threadIdx.x;
  __shared__ int h2[256];
  __shared__ int cur[256];
  __shared__ float dg[256];
  int base = Gs[bin * NBLK];
  int end  = (bin + 1 < NBC) ? Gs[(bin + 1) * NBLK] : E;
  int m = end - base;
  if (tid < 256) { h2[tid] = 0; dg[tid] = 0.f; }
  __syncthreads();
  // phase 1: fine histogram of dst&255
  for (int i = tid; i < m; i += 512) {
    unsigned sd = (unsigned)bufA[base + i].y;
    atomicAdd(&h2[sd & 255], 1);
  }
  __syncthreads();
  int own = (tid < 256) ? h2[tid] : 0;
  // inclusive Hillis-Steele scan over 256 bins
  for (int o = 1; o < 256; o <<= 1) {
    int u = 0;
    if (tid < 256 && tid >= o) u = h2[tid - o];
    __syncthreads();
    if (tid < 256) h2[tid] += u;
    __syncthreads();
  }
  int nd = (bin << 8) + tid;
  if (tid < 256) {
    int excl = h2[tid] - own;
    cur[tid] = excl;
    if (nd < N) offs[nd] = base + excl;
  }
  if (bin == NBC - 1 && tid == 0) offs[N] = E;
  __syncthreads();
  // phase 2: scatter into dst-grouped order + weighted degree
  for (int i = tid; i < m; i += 512) {
    int2 r = bufA[base + i];
    unsigned sd = (unsigned)r.y;
    int dl = (int)(sd & 255u);
    int p = atomicAdd(&cur[dl], 1);
    bufB[base + p] = r;
    atomicAdd(&dg[dl], __int_as_float(r.x));
  }
  __syncthreads();
  if (tid < 256 && nd < N) dinv[nd] = rsqrtf(1.0f + dg[tid]);  // self-loop w=1; deg>=1
}

// ============ norm prepass: record (ew, src|dst) -> (norm, src) ============

__global__ __launch_bounds__(256) void k_norm(int2* __restrict__ recs,
                                              const float* __restrict__ dinv, int E) {
  int e = blockIdx.x * 256 + threadIdx.x;
  if (e < E) {
    int2 r = recs[e];
    unsigned sd = (unsigned)r.y;
    int s = (int)(sd >> 16), d = (int)(sd & 0xffffu);
    float nrm = dinv[s] * __int_as_float(r.x) * dinv[d];
    recs[e] = make_int2(__float_as_int(nrm), s);
  }
}

// ============ weight transpose: WT[d*64 + j] = W[j*K + d] (tiny) ============

__global__ __launch_bounds__(256) void k_transW(const float* __restrict__ W,
                                                float* __restrict__ WT, int K) {
  int idx = blockIdx.x * 256 + threadIdx.x;
  if (idx < K * 64) {
    int d = idx >> 6, j = idx & 63;
    WT[idx] = W[j * K + d];
  }
}

// ============ GEMM v2: out[N][64] = X[N][K] @ W[64][K]^T, bf16 output ============
// W pre-transposed in global (WTg[d][j]); both LDS tiles staged with
// consecutive-lane -> consecutive-word float4 writes (conflict-free) and
// float4 global reads. X tile row-major [m][d] (no transpose). Inner loop
// 4-wide in d: 8 b128 LDS reads per 64 FMAs -> VALU-bound.

template <int K>
__global__ __launch_bounds__(256) void k_gemm(const float* __restrict__ X,
                                              const float* __restrict__ WTg,
                                              u16* __restrict__ out, int n_nodes) {
  constexpr int PAD = 68;                 // float4-aligned row stride
  __shared__ float XT[64 * PAD];          // XT[m][d]  (row-major)
  __shared__ float WL[64 * PAD];          // WL[d][j]
  const int tid = threadIdx.x;
  const int n0 = blockIdx.x * 64;
  const int tx = tid & 15;                // feature group: j = 4*tx + ji
  const int ty = tid >> 4;                // node group:    m = 4*ty + mi
  float acc[4][4] = {{0.f}};

  for (int ph = 0; ph < K / 64; ++ph) {
    const int d0 = ph * 64;
    __syncthreads();
#pragma unroll
    for (int k = 0; k < 4; ++k) {
      int f = tid + k * 256;              // 0..1023 float4 slots per tile
      int r = f >> 4, q = f & 15;         // r = row, q = float4 column
      // X tile: row m=r, cols d0+4q..+3  (coalesced read, contiguous write)
      int n = n0 + r;
      float4 xv = (n < n_nodes)
        ? *reinterpret_cast<const float4*>(&X[(size_t)n * K + d0 + 4 * q])
        : make_float4(0.f, 0.f, 0.f, 0.f);
      *reinterpret_cast<float4*>(&XT[r * PAD + 4 * q]) = xv;
      // W tile: row d=r, cols 4q..+3
      float4 wv = *reinterpret_cast<const float4*>(&WTg[(size_t)(d0 + r) * 64 + 4 * q]);
      *reinterpret_cast<float4*>(&WL[r * PAD + 4 * q]) = wv;
    }
    __syncthreads();
#pragma unroll 4
    for (int dd = 0; dd < 64; dd += 4) {
      float4 xs[4], ws[4];
#pragma unroll
      for (int mi = 0; mi < 4; ++mi)
        xs[mi] = *reinterpret_cast<const float4*>(&XT[(4 * ty + mi) * PAD + dd]);
#pragma unroll
      for (int dk = 0; dk < 4; ++dk)
        ws[dk] = *reinterpret_cast<const float4*>(&WL[(dd + dk) * PAD + 4 * tx]);
#pragma unroll
      for (int mi = 0; mi < 4; ++mi) {
        float xm[4] = {xs[mi].x, xs[mi].y, xs[mi].z, xs[mi].w};
#pragma unroll
        for (int dk = 0; dk < 4; ++dk) {
          acc[mi][0] = fmaf(xm[dk], ws[dk].x, acc[mi][0]);
          acc[mi][1] = fmaf(xm[dk], ws[dk].y, acc[mi][1]);
          acc[mi][2] = fmaf(xm[dk], ws[dk].z, acc[mi][2]);
          acc[mi][3] = fmaf(xm[dk], ws[dk].w, acc[mi][3]);
        }
      }
    }
  }

#pragma unroll
  for (int mi = 0; mi < 4; ++mi) {
    int n = n0 + 4 * ty + mi;
    if (n < n_nodes) {
      ushort4 o = make_ushort4(f2bf(acc[mi][0]), f2bf(acc[mi][1]),
                               f2bf(acc[mi][2]), f2bf(acc[mi][3]));
      *reinterpret_cast<ushort4*>(&out[(size_t)n * HID + 4 * tx]) = o;
    }
  }
}

// ============ aggregation v3: one wave per node, 4 edges per wave-instruction,
// deep gather pipeline (8 gathers in flight in the 32-edge main block) ============
// Wave = 4 groups x 16 lanes. Group g handles edge i+4k+g; lane covers 4
// features via one 8B (4x bf16) load. Epilogue: shfl_xor(16,32) group-reduce,
// lanes 0-15 write float4.

__device__ __forceinline__ void bfma(uint2 v, float w,
                                     float& a0, float& a1, float& a2, float& a3) {
  a0 = fmaf(__uint_as_float(v.x << 16), w, a0);
  a1 = fmaf(__uint_as_float(v.x & 0xffff0000u), w, a1);
  a2 = fmaf(__uint_as_float(v.y << 16), w, a2);
  a3 = fmaf(__uint_as_float(v.y & 0xffff0000u), w, a3);
}

__global__ __launch_bounds__(256) void k_agg(const u16* __restrict__ h,
                                             const int2* __restrict__ recs,
                                             const int* __restrict__ offs,
                                             const float* __restrict__ dinv,
                                             const float* __restrict__ bias,
                                             const float* __restrict__ resid,
                                             float* __restrict__ out, int n_nodes, int mode) {
  int gw = __builtin_amdgcn_readfirstlane((int)((blockIdx.x * 256 + threadIdx.x) >> 6));
  if (gw >= n_nodes) return;
  int lane = threadIdx.x & 63;
  int g = lane >> 4;                  // edge group 0..3
  int p4 = (lane & 15) * 4;           // feature base (4 features per lane)
  int beg = __builtin_amdgcn_readfirstlane(offs[gw]);
  int end = __builtin_amdgcn_readfirstlane(offs[gw + 1]);
  float di = dinv[gw];

  float a0 = 0.f, a1 = 0.f, a2 = 0.f, a3 = 0.f;
  float b0 = 0.f, b1 = 0.f, b2 = 0.f, b3 = 0.f;

  // self loop (weight di*di, counted once via group 0)
  {
    uint2 v = *reinterpret_cast<const uint2*>(&h[(size_t)gw * HID + p4]);
    bfma(v, (g == 0) ? di * di : 0.f, a0, a1, a2, a3);
  }

  int i = beg;
  for (; i + 32 <= end; i += 32) {     // 8 gathers in flight
    int2 r0 = recs[i + g];       int2 r1 = recs[i + 4 + g];
    int2 r2 = recs[i + 8 + g];   int2 r3 = recs[i + 12 + g];
    int2 r4 = recs[i + 16 + g];  int2 r5 = recs[i + 20 + g];
    int2 r6 = recs[i + 24 + g];  int2 r7 = recs[i + 28 + g];
    uint2 v0 = *reinterpret_cast<const uint2*>(&h[(size_t)r0.y * HID + p4]);
    uint2 v1 = *reinterpret_cast<const uint2*>(&h[(size_t)r1.y * HID + p4]);
    uint2 v2 = *reinterpret_cast<const uint2*>(&h[(size_t)r2.y * HID + p4]);
    uint2 v3 = *reinterpret_cast<const uint2*>(&h[(size_t)r3.y * HID + p4]);
    uint2 v4 = *reinterpret_cast<const uint2*>(&h[(size_t)r4.y * HID + p4]);
    uint2 v5 = *reinterpret_cast<const uint2*>(&h[(size_t)r5.y * HID + p4]);
    uint2 v6 = *reinterpret_cast<const uint2*>(&h[(size_t)r6.y * HID + p4]);
    uint2 v7 = *reinterpret_cast<const uint2*>(&h[(size_t)r7.y * HID + p4]);
    bfma(v0, __int_as_float(r0.x), a0, a1, a2, a3);
    bfma(v1, __int_as_float(r1.x), b0, b1, b2, b3);
    bfma(v2, __int_as_float(r2.x), a0, a1, a2, a3);
    bfma(v3, __int_as_float(r3.x), b0, b1, b2, b3);
    bfma(v4, __int_as_float(r4.x), a0, a1, a2, a3);
    bfma(v5, __int_as_float(r5.x), b0, b1, b2, b3);
    bfma(v6, __int_as_float(r6.x), a0, a1, a2, a3);
    bfma(v7, __int_as_float(r7.x), b0, b1, b2, b3);
  }
  if (i + 16 <= end) {                 // 4 gathers in flight
    int2 r0 = recs[i + g];       int2 r1 = recs[i + 4 + g];
    int2 r2 = recs[i + 8 + g];   int2 r3 = recs[i + 12 + g];
    uint2 v0 = *reinterpret_cast<const uint2*>(&h[(size_t)r0.y * HID + p4]);
    uint2 v1 = *reinterpret_cast<const uint2*>(&h[(size_t)r1.y * HID + p4]);
    uint2 v2 = *reinterpret_cast<const uint2*>(&h[(size_t)r2.y * HID + p4]);
    uint2 v3 = *reinterpret_cast<const uint2*>(&h[(size_t)r3.y * HID + p4]);
    bfma(v0, __int_as_float(r0.x), a0, a1, a2, a3);
    bfma(v1, __int_as_float(r1.x), b0, b1, b2, b3);
    bfma(v2, __int_as_float(r2.x), a0, a1, a2, a3);
    bfma(v3, __int_as_float(r3.x), b0, b1, b2, b3);
    i += 16;
  }
  if (i + 8 <= end) {
    int2 r0 = recs[i + g];       int2 r1 = recs[i + 4 + g];
    uint2 v0 = *reinterpret_cast<const uint2*>(&h[(size_t)r0.y * HID + p4]);
    uint2 v1 = *reinterpret_cast<const uint2*>(&h[(size_t)r1.y * HID + p4]);
    bfma(v0, __int_as_float(r0.x), a0, a1, a2, a3);
    bfma(v1, __int_as_float(r1.x), b0, b1, b2, b3);
    i += 8;
  }
  if (i + 4 <= end) {
    int2 r0 = recs[i + g];
    uint2 v0 = *reinterpret_cast<const uint2*>(&h[(size_t)r0.y * HID + p4]);
    bfma(v0, __int_as_float(r0.x), a0, a1, a2, a3);
    i += 4;
  }
  if (i < end) {                       // masked tail, rem in 1..3
    int rem = end - i;
    int idx = i + ((g < rem) ? g : (rem - 1));
    int2 r = recs[idx];
    float w = (g < rem) ? __int_as_float(r.x) : 0.f;
    uint2 v = *reinterpret_cast<const uint2*>(&h[(size_t)r.y * HID + p4]);
    bfma(v, w, b0, b1, b2, b3);
  }

  float r0 = a0 + b0, r1 = a1 + b1, r2 = a2 + b2, r3 = a3 + b3;
  r0 += __shfl_xor(r0, 16); r0 += __shfl_xor(r0, 32);
  r1 += __shfl_xor(r1, 16); r1 += __shfl_xor(r1, 32);
  r2 += __shfl_xor(r2, 16); r2 += __shfl_xor(r2, 32);
  r3 += __shfl_xor(r3, 16); r3 += __shfl_xor(r3, 32);

  if (g == 0) {
    float4 bb = *reinterpret_cast<const float4*>(&bias[p4]);
    r0 += bb.x; r1 += bb.y; r2 += bb.z; r3 += bb.w;
    if (mode == 0) {
      r0 = fmaxf(r0, 0.f); r1 = fmaxf(r1, 0.f);
      r2 = fmaxf(r2, 0.f); r3 = fmaxf(r3, 0.f);
    } else {
      float4 rs = *reinterpret_cast<const float4*>(&resid[(size_t)gw * HID + p4]);
      r0 += rs.x; r1 += rs.y; r2 += rs.z; r3 += rs.w;
    }
    *reinterpret_cast<float4*>(&out[(size_t)gw * HID + p4]) = make_float4(r0, r1, r2, r3);
  }
}

// ============ launcher ============

extern "C" void kernel_launch(void* const* d_in, const int* in_sizes, int n_in,
                              void* d_out, int out_size, void* d_ws, size_t ws_size,
                              hipStream_t stream) {
  const float* x  = (const float*)d_in[0];
  const int*   ei = (const int*)d_in[1];
  const float* ew = (const float*)d_in[2];
  const float* W1 = (const float*)d_in[3];
  const float* b1 = (const float*)d_in[4];
  const float* W2 = (const float*)d_in[5];
  const float* b2 = (const float*)d_in[6];
  float* out = (float*)d_out;

  const int N = in_sizes[0] / DIN;
  const int E = in_sizes[2];
  const int* src = ei;        // ei shape (2,E) row-major
  const int* dst = ei + E;

  const int NBC = (N + 255) >> 8;          // coarse buckets (196 for N=50000)
  const int L = NBC * NBLK;                // G length
  const int chunk = (E + NBLK - 1) / NBLK;
  const int nch = (L + 2047) / 2048;       // scan chunks (<=64)

  char* p = (char*)d_ws;
  auto carve = [&](size_t bytes) {
    char* r = p;
    p += (bytes + 255) & ~(size_t)255;
    return r;
  };
  int*   G     = (int*)carve((size_t)L * 4);
  int*   bsum  = (int*)carve(64 * 4);
  int*   offs  = (int*)carve((size_t)(N + 1) * 4);
  float* dinv  = (float*)carve((size_t)N * 4);
  int2*  bufA  = (int2*)carve((size_t)E * 8);
  int2*  bufB  = (int2*)carve((size_t)E * 8);
  u16*   h     = (u16*)carve((size_t)N * HID * 2);   // bf16 linear outputs (gathered)
  float* h1    = (float*)carve((size_t)N * HID * 4); // fp32 layer-1 activations
  float* WT1   = (float*)carve((size_t)DIN * HID * 4);
  float* WT2   = (float*)carve((size_t)HID * HID * 4);

  int gblk = (N + 63) / 64;
  int ablk = (N + 3) / 4;

  // ---- build (zero global atomics) + weight transposes ----
  k_histA<<<NBLK, 512, 0, stream>>>(dst, G, E, NBC, chunk);
  k_transW<<<(DIN * HID + 255) / 256, 256, 0, stream>>>(W1, WT1, DIN);
  k_transW<<<(HID * HID + 255) / 256, 256, 0, stream>>>(W2, WT2, HID);
  k_chunksum<<<nch, 256, 0, stream>>>(G, bsum, L);
  k_scanbsum<<<1, 64, 0, stream>>>(bsum, nch);
  k_scanfinal<<<nch, 256, 0, stream>>>(G, bsum, L);
  k_scatterA<<<NBLK, 512, 0, stream>>>(src, dst, ew, G, bufA, E, NBC, chunk);
  k_passB<<<NBC, 512, 0, stream>>>(bufA, G, bufB, offs, dinv, NBC, E, N);
  k_norm<<<(E + 255) / 256, 256, 0, stream>>>(bufB, dinv, E);

  // ---- layer 1 ----
  k_gemm<DIN><<<gblk, 256, 0, stream>>>(x, WT1, h, N);
  k_agg<<<ablk, 256, 0, stream>>>(h, bufB, offs, dinv, b1, nullptr, h1, N, 0);
  // ---- layer 2 (reuse h buffer for h1 @ W2^T) ----
  k_gemm<HID><<<gblk, 256, 0, stream>>>(h1, WT2, h, N);
  k_agg<<<ablk, 256, 0, stream>>>(h, bufB, offs, dinv, b2, h1, out, N, 1);
}

// Round 8
// 233.075 us; speedup vs baseline: 2.6016x; 1.0493x over previous
//
#include <hip/hip_runtime.h>

#define HID 64
#define DIN 128
#define NBLK 512                // blocks for hist/scatter passes

typedef unsigned long long ull;
typedef unsigned short u16;

static __device__ __forceinline__ u16 f2bf(float f) {
  unsigned u = __float_as_uint(f);
  unsigned lsb = (u >> 16) & 1u;
  u += 0x7fffu + lsb;
  return (u16)(u >> 16);
}

// ============ build pass A: coarse histogram (bucket = dst>>8) ============

__global__ __launch_bounds__(512) void k_histA(const int* __restrict__ dst,
                                               int* __restrict__ G,
                                               int E, int NBC, int chunk) {
  __shared__ int h[256];
  int b = blockIdx.x, tid = threadIdx.x;
  if (tid < 256) h[tid] = 0;
  __syncthreads();
  int e0 = b * chunk, e1 = min(E, e0 + chunk);
  for (int e = e0 + tid; e < e1; e += 512) atomicAdd(&h[dst[e] >> 8], 1);
  __syncthreads();
  if (tid < NBC) G[tid * NBLK + b] = h[tid];   // bin-major for counting-sort scan
}

// ============ exclusive scan of G (L = NBC*NBLK elems), chunk=2048 ============

__global__ __launch_bounds__(256) void k_chunksum(const int* __restrict__ G, int* bsum, int L) {
  int b = blockIdx.x, t = threadIdx.x;
  int base = b * 2048;
  int s = 0;
  for (int i = t; i < 2048; i += 256) {
    int g = base + i;
    s += (g < L) ? G[g] : 0;
  }
  __shared__ int red[4];
  for (int o = 32; o > 0; o >>= 1) s += __shfl_down(s, o);
  if ((t & 63) == 0) red[t >> 6] = s;
  __syncthreads();
  if (t == 0) bsum[b] = red[0] + red[1] + red[2] + red[3];
}

__global__ __launch_bounds__(64) void k_scanbsum(int* bsum, int nb) {
  int lane = threadIdx.x;
  int v = (lane < nb) ? bsum[lane] : 0;
  int incl = v;
  for (int o = 1; o < 64; o <<= 1) {
    int u = __shfl_up(incl, o);
    if (lane >= o) incl += u;
  }
  if (lane < nb) bsum[lane] = incl - v;   // exclusive
}

__global__ __launch_bounds__(256) void k_scanfinal(int* G, const int* __restrict__ bsum, int L) {
  int b = blockIdx.x, t = threadIdx.x;
  int i0 = b * 2048 + t * 8;
  int v[8], tsum = 0;
#pragma unroll
  for (int k = 0; k < 8; ++k) {
    v[k] = (i0 + k < L) ? G[i0 + k] : 0;
    tsum += v[k];
  }
  int incl = tsum;
  for (int o = 1; o < 64; o <<= 1) {
    int u = __shfl_up(incl, o);
    if ((t & 63) >= o) incl += u;
  }
  int wexcl = incl - tsum;
  __shared__ int wtot[4];
  int w = t >> 6;
  if ((t & 63) == 63) wtot[w] = incl;
  __syncthreads();
  int wbase = 0;
  for (int i = 0; i < w; ++i) wbase += wtot[i];
  int run = bsum[b] + wbase + wexcl;
#pragma unroll
  for (int k = 0; k < 8; ++k) {
    if (i0 + k < L) G[i0 + k] = run;      // in-place: v[] already read
    run += v[k];
  }
}

// ============ pass A scatter: coarse-bucketed records, LDS cursors ============
// record int2 = ( float_bits(ew), (src<<16)|dst )

__global__ __launch_bounds__(512) void k_scatterA(const int* __restrict__ src,
                                                  const int* __restrict__ dst,
                                                  const float* __restrict__ ew,
                                                  const int* __restrict__ Gs,
                                                  int2* __restrict__ bufA,
                                                  int E, int NBC, int chunk) {
  __shared__ int cur[256];                 // NBC <= 256 (N <= 65536)
  int b = blockIdx.x, tid = threadIdx.x;
  if (tid < NBC) cur[tid] = Gs[tid * NBLK + b];   // this block's reserved run per bucket
  __syncthreads();
  int e0 = b * chunk, e1 = min(E, e0 + chunk);
  for (int e = e0 + tid; e < e1; e += 512) {
    int s = src[e], d = dst[e];
    float w = ew[e];
    int p = atomicAdd(&cur[d >> 8], 1);
    bufA[p] = make_int2(__float_as_int(w), (int)(((unsigned)s << 16) | (unsigned)d));
  }
}

// ============ pass B: one block per coarse bucket -> dst-grouped + offs + dinv ============

__global__ __launch_bounds__(512) void k_passB(const int2* __restrict__ bufA,
                                               const int* __restrict__ Gs,
                                               int2* __restrict__ bufB,
                                               int* __restrict__ offs,
                                               float* __restrict__ dinv,
                                               int NBC, int E, int N) {
  int bin = blockIdx.x, tid = threadIdx.x;
  __shared__ int h2[256];
  __shared__ int cur[256];
  __shared__ float dg[256];
  int base = Gs[bin * NBLK];
  int end  = (bin + 1 < NBC) ? Gs[(bin + 1) * NBLK] : E;
  int m = end - base;
  if (tid < 256) { h2[tid] = 0; dg[tid] = 0.f; }
  __syncthreads();
  // phase 1: fine histogram of dst&255
  for (int i = tid; i < m; i += 512) {
    unsigned sd = (unsigned)bufA[base + i].y;
    atomicAdd(&h2[sd & 255], 1);
  }
  __syncthreads();
  int own = (tid < 256) ? h2[tid] : 0;
  // inclusive Hillis-Steele scan over 256 bins
  for (int o = 1; o < 256; o <<= 1) {
    int u = 0;
    if (tid < 256 && tid >= o) u = h2[tid - o];
    __syncthreads();
    if (tid < 256) h2[tid] += u;
    __syncthreads();
  }
  int nd = (bin << 8) + tid;
  if (tid < 256) {
    int excl = h2[tid] - own;
    cur[tid] = excl;
    if (nd < N) offs[nd] = base + excl;
  }
  if (bin == NBC - 1 && tid == 0) offs[N] = E;
  __syncthreads();
  // phase 2: scatter into dst-grouped order + weighted degree
  for (int i = tid; i < m; i += 512) {
    int2 r = bufA[base + i];
    unsigned sd = (unsigned)r.y;
    int dl = (int)(sd & 255u);
    int p = atomicAdd(&cur[dl], 1);
    bufB[base + p] = r;
    atomicAdd(&dg[dl], __int_as_float(r.x));
  }
  __syncthreads();
  if (tid < 256 && nd < N) dinv[nd] = rsqrtf(1.0f + dg[tid]);  // self-loop w=1; deg>=1
}

// ============ norm prepass: record (ew, src|dst) -> (norm, src) ============

__global__ __launch_bounds__(256) void k_norm(int2* __restrict__ recs,
                                              const float* __restrict__ dinv, int E) {
  int e = blockIdx.x * 256 + threadIdx.x;
  if (e < E) {
    int2 r = recs[e];
    unsigned sd = (unsigned)r.y;
    int s = (int)(sd >> 16), d = (int)(sd & 0xffffu);
    float nrm = dinv[s] * __int_as_float(r.x) * dinv[d];
    recs[e] = make_int2(__float_as_int(nrm), s);
  }
}

// ============ weight transposes (both layers, one launch) ============

__global__ __launch_bounds__(256) void k_transW2(const float* __restrict__ W1,
                                                 const float* __restrict__ W2,
                                                 float* __restrict__ WT1,
                                                 float* __restrict__ WT2) {
  int idx = blockIdx.x * 256 + threadIdx.x;
  if (idx < DIN * 64) {
    int d = idx >> 6, j = idx & 63;
    WT1[idx] = W1[j * DIN + d];
  }
  int i2 = idx - DIN * 64;
  if (i2 >= 0 && i2 < HID * 64) {
    int d = i2 >> 6, j = i2 & 63;
    WT2[i2] = W2[j * HID + d];
  }
}

// ============ GEMM v2: out[N][64] = X[N][K] @ W[64][K]^T, bf16 output ============
// W pre-transposed in global (WTg[d][j]); both LDS tiles staged with
// consecutive-lane -> consecutive-word float4 writes (conflict-free) and
// float4 global reads. X tile row-major [m][d] (no transpose). Inner loop
// 4-wide in d: 8 b128 LDS reads per 64 FMAs -> VALU-bound.

template <int K>
__global__ __launch_bounds__(256) void k_gemm(const float* __restrict__ X,
                                              const float* __restrict__ WTg,
                                              u16* __restrict__ out, int n_nodes) {
  constexpr int PAD = 68;                 // float4-aligned row stride
  __shared__ float XT[64 * PAD];          // XT[m][d]  (row-major)
  __shared__ float WL[64 * PAD];          // WL[d][j]
  const int tid = threadIdx.x;
  const int n0 = blockIdx.x * 64;
  const int tx = tid & 15;                // feature group: j = 4*tx + ji
  const int ty = tid >> 4;                // node group:    m = 4*ty + mi
  float acc[4][4] = {{0.f}};

  for (int ph = 0; ph < K / 64; ++ph) {
    const int d0 = ph * 64;
    __syncthreads();
#pragma unroll
    for (int k = 0; k < 4; ++k) {
      int f = tid + k * 256;              // 0..1023 float4 slots per tile
      int r = f >> 4, q = f & 15;         // r = row, q = float4 column
      int n = n0 + r;
      float4 xv = (n < n_nodes)
        ? *reinterpret_cast<const float4*>(&X[(size_t)n * K + d0 + 4 * q])
        : make_float4(0.f, 0.f, 0.f, 0.f);
      *reinterpret_cast<float4*>(&XT[r * PAD + 4 * q]) = xv;
      float4 wv = *reinterpret_cast<const float4*>(&WTg[(size_t)(d0 + r) * 64 + 4 * q]);
      *reinterpret_cast<float4*>(&WL[r * PAD + 4 * q]) = wv;
    }
    __syncthreads();
#pragma unroll 4
    for (int dd = 0; dd < 64; dd += 4) {
      float4 xs[4], ws[4];
#pragma unroll
      for (int mi = 0; mi < 4; ++mi)
        xs[mi] = *reinterpret_cast<const float4*>(&XT[(4 * ty + mi) * PAD + dd]);
#pragma unroll
      for (int dk = 0; dk < 4; ++dk)
        ws[dk] = *reinterpret_cast<const float4*>(&WL[(dd + dk) * PAD + 4 * tx]);
#pragma unroll
      for (int mi = 0; mi < 4; ++mi) {
        float xm[4] = {xs[mi].x, xs[mi].y, xs[mi].z, xs[mi].w};
#pragma unroll
        for (int dk = 0; dk < 4; ++dk) {
          acc[mi][0] = fmaf(xm[dk], ws[dk].x, acc[mi][0]);
          acc[mi][1] = fmaf(xm[dk], ws[dk].y, acc[mi][1]);
          acc[mi][2] = fmaf(xm[dk], ws[dk].z, acc[mi][2]);
          acc[mi][3] = fmaf(xm[dk], ws[dk].w, acc[mi][3]);
        }
      }
    }
  }

#pragma unroll
  for (int mi = 0; mi < 4; ++mi) {
    int n = n0 + 4 * ty + mi;
    if (n < n_nodes) {
      ushort4 o = make_ushort4(f2bf(acc[mi][0]), f2bf(acc[mi][1]),
                               f2bf(acc[mi][2]), f2bf(acc[mi][3]));
      *reinterpret_cast<ushort4*>(&out[(size_t)n * HID + 4 * tx]) = o;
    }
  }
}

// ============ aggregation v4: quarter-wave per node ============
// Wave = 4 independent 16-lane groups; group q owns node (waveid*4+q) fully
// (16 lanes x 4 feats, 8B bf16x4 loads). Unroll-8 main loop: 8 gathers in
// flight PER GROUP (up to 32/wave) for any deg>=8. Cascade 4/2/1 tails have
// zero wasted gathers (uniform-per-group branches). No shuffle epilogue:
// each group writes its node's float4 directly.
// mode 0: out = relu(agg + bias)          (layer 1 -> h1, fp32)
// mode 1: out = agg + bias + resid        (layer 2 -> final, fp32)

__device__ __forceinline__ void bfma(uint2 v, float w,
                                     float& a0, float& a1, float& a2, float& a3) {
  a0 = fmaf(__uint_as_float(v.x << 16), w, a0);
  a1 = fmaf(__uint_as_float(v.x & 0xffff0000u), w, a1);
  a2 = fmaf(__uint_as_float(v.y << 16), w, a2);
  a3 = fmaf(__uint_as_float(v.y & 0xffff0000u), w, a3);
}

__global__ __launch_bounds__(256) void k_agg(const u16* __restrict__ h,
                                             const int2* __restrict__ recs,
                                             const int* __restrict__ offs,
                                             const float* __restrict__ dinv,
                                             const float* __restrict__ bias,
                                             const float* __restrict__ resid,
                                             float* __restrict__ out, int n_nodes, int mode) {
  int tid = threadIdx.x;
  int lane = tid & 63;
  int q = lane >> 4;                  // group 0..3
  int p4 = (lane & 15) * 4;           // feature base
  int node = (blockIdx.x * 4 + (tid >> 6)) * 4 + q;   // 16 nodes per block
  if (node >= n_nodes) return;
  int beg = offs[node], end = offs[node + 1];
  float di = dinv[node];

  float a0, a1, a2, a3;               // self loop seeds a-chain
  float b0 = 0.f, b1 = 0.f, b2 = 0.f, b3 = 0.f;
  {
    uint2 v = *reinterpret_cast<const uint2*>(&h[(size_t)node * HID + p4]);
    float w = di * di;
    a0 = __uint_as_float(v.x << 16) * w;
    a1 = __uint_as_float(v.x & 0xffff0000u) * w;
    a2 = __uint_as_float(v.y << 16) * w;
    a3 = __uint_as_float(v.y & 0xffff0000u) * w;
  }

  int i = beg;
  while (i + 8 <= end) {              // 8 gathers in flight per group
    int2 r0 = recs[i];     int2 r1 = recs[i + 1];
    int2 r2 = recs[i + 2]; int2 r3 = recs[i + 3];
    int2 r4 = recs[i + 4]; int2 r5 = recs[i + 5];
    int2 r6 = recs[i + 6]; int2 r7 = recs[i + 7];
    uint2 v0 = *reinterpret_cast<const uint2*>(&h[(size_t)r0.y * HID + p4]);
    uint2 v1 = *reinterpret_cast<const uint2*>(&h[(size_t)r1.y * HID + p4]);
    uint2 v2 = *reinterpret_cast<const uint2*>(&h[(size_t)r2.y * HID + p4]);
    uint2 v3 = *reinterpret_cast<const uint2*>(&h[(size_t)r3.y * HID + p4]);
    uint2 v4 = *reinterpret_cast<const uint2*>(&h[(size_t)r4.y * HID + p4]);
    uint2 v5 = *reinterpret_cast<const uint2*>(&h[(size_t)r5.y * HID + p4]);
    uint2 v6 = *reinterpret_cast<const uint2*>(&h[(size_t)r6.y * HID + p4]);
    uint2 v7 = *reinterpret_cast<const uint2*>(&h[(size_t)r7.y * HID + p4]);
    bfma(v0, __int_as_float(r0.x), a0, a1, a2, a3);
    bfma(v1, __int_as_float(r1.x), b0, b1, b2, b3);
    bfma(v2, __int_as_float(r2.x), a0, a1, a2, a3);
    bfma(v3, __int_as_float(r3.x), b0, b1, b2, b3);
    bfma(v4, __int_as_float(r4.x), a0, a1, a2, a3);
    bfma(v5, __int_as_float(r5.x), b0, b1, b2, b3);
    bfma(v6, __int_as_float(r6.x), a0, a1, a2, a3);
    bfma(v7, __int_as_float(r7.x), b0, b1, b2, b3);
    i += 8;
  }
  if (i + 4 <= end) {
    int2 r0 = recs[i];     int2 r1 = recs[i + 1];
    int2 r2 = recs[i + 2]; int2 r3 = recs[i + 3];
    uint2 v0 = *reinterpret_cast<const uint2*>(&h[(size_t)r0.y * HID + p4]);
    uint2 v1 = *reinterpret_cast<const uint2*>(&h[(size_t)r1.y * HID + p4]);
    uint2 v2 = *reinterpret_cast<const uint2*>(&h[(size_t)r2.y * HID + p4]);
    uint2 v3 = *reinterpret_cast<const uint2*>(&h[(size_t)r3.y * HID + p4]);
    bfma(v0, __int_as_float(r0.x), a0, a1, a2, a3);
    bfma(v1, __int_as_float(r1.x), b0, b1, b2, b3);
    bfma(v2, __int_as_float(r2.x), a0, a1, a2, a3);
    bfma(v3, __int_as_float(r3.x), b0, b1, b2, b3);
    i += 4;
  }
  if (i + 2 <= end) {
    int2 r0 = recs[i];     int2 r1 = recs[i + 1];
    uint2 v0 = *reinterpret_cast<const uint2*>(&h[(size_t)r0.y * HID + p4]);
    uint2 v1 = *reinterpret_cast<const uint2*>(&h[(size_t)r1.y * HID + p4]);
    bfma(v0, __int_as_float(r0.x), a0, a1, a2, a3);
    bfma(v1, __int_as_float(r1.x), b0, b1, b2, b3);
    i += 2;
  }
  if (i < end) {
    int2 r0 = recs[i];
    uint2 v0 = *reinterpret_cast<const uint2*>(&h[(size_t)r0.y * HID + p4]);
    bfma(v0, __int_as_float(r0.x), a0, a1, a2, a3);
  }

  float r0 = a0 + b0, r1 = a1 + b1, r2 = a2 + b2, r3 = a3 + b3;
  float4 bb = *reinterpret_cast<const float4*>(&bias[p4]);
  r0 += bb.x; r1 += bb.y; r2 += bb.z; r3 += bb.w;
  if (mode == 0) {
    r0 = fmaxf(r0, 0.f); r1 = fmaxf(r1, 0.f);
    r2 = fmaxf(r2, 0.f); r3 = fmaxf(r3, 0.f);
  } else {
    float4 rs = *reinterpret_cast<const float4*>(&resid[(size_t)node * HID + p4]);
    r0 += rs.x; r1 += rs.y; r2 += rs.z; r3 += rs.w;
  }
  *reinterpret_cast<float4*>(&out[(size_t)node * HID + p4]) = make_float4(r0, r1, r2, r3);
}

// ============ launcher ============

extern "C" void kernel_launch(void* const* d_in, const int* in_sizes, int n_in,
                              void* d_out, int out_size, void* d_ws, size_t ws_size,
                              hipStream_t stream) {
  const float* x  = (const float*)d_in[0];
  const int*   ei = (const int*)d_in[1];
  const float* ew = (const float*)d_in[2];
  const float* W1 = (const float*)d_in[3];
  const float* b1 = (const float*)d_in[4];
  const float* W2 = (const float*)d_in[5];
  const float* b2 = (const float*)d_in[6];
  float* out = (float*)d_out;

  const int N = in_sizes[0] / DIN;
  const int E = in_sizes[2];
  const int* src = ei;        // ei shape (2,E) row-major
  const int* dst = ei + E;

  const int NBC = (N + 255) >> 8;          // coarse buckets (196 for N=50000)
  const int L = NBC * NBLK;                // G length
  const int chunk = (E + NBLK - 1) / NBLK;
  const int nch = (L + 2047) / 2048;       // scan chunks (<=64)

  char* p = (char*)d_ws;
  auto carve = [&](size_t bytes) {
    char* r = p;
    p += (bytes + 255) & ~(size_t)255;
    return r;
  };
  int*   G     = (int*)carve((size_t)L * 4);
  int*   bsum  = (int*)carve(64 * 4);
  int*   offs  = (int*)carve((size_t)(N + 1) * 4);
  float* dinv  = (float*)carve((size_t)N * 4);
  int2*  bufA  = (int2*)carve((size_t)E * 8);
  int2*  bufB  = (int2*)carve((size_t)E * 8);
  u16*   h     = (u16*)carve((size_t)N * HID * 2);   // bf16 linear outputs (gathered)
  float* h1    = (float*)carve((size_t)N * HID * 4); // fp32 layer-1 activations
  float* WT1   = (float*)carve((size_t)DIN * HID * 4);
  float* WT2   = (float*)carve((size_t)HID * HID * 4);

  int gblk = (N + 63) / 64;
  int ablk = (N + 15) / 16;                // 16 nodes per 256-thread block

  // ---- build (zero global atomics) + weight transposes ----
  k_histA<<<NBLK, 512, 0, stream>>>(dst, G, E, NBC, chunk);
  k_transW2<<<((DIN + HID) * 64 + 255) / 256, 256, 0, stream>>>(W1, W2, WT1, WT2);
  k_chunksum<<<nch, 256, 0, stream>>>(G, bsum, L);
  k_scanbsum<<<1, 64, 0, stream>>>(bsum, nch);
  k_scanfinal<<<nch, 256, 0, stream>>>(G, bsum, L);
  k_scatterA<<<NBLK, 512, 0, stream>>>(src, dst, ew, G, bufA, E, NBC, chunk);
  k_passB<<<NBC, 512, 0, stream>>>(bufA, G, bufB, offs, dinv, NBC, E, N);
  k_norm<<<(E + 255) / 256, 256, 0, stream>>>(bufB, dinv, E);

  // ---- layer 1 ----
  k_gemm<DIN><<<gblk, 256, 0, stream>>>(x, WT1, h, N);
  k_agg<<<ablk, 256, 0, stream>>>(h, bufB, offs, dinv, b1, nullptr, h1, N, 0);
  // ---- layer 2 (reuse h buffer for h1 @ W2^T) ----
  k_gemm<HID><<<gblk, 256, 0, stream>>>(h1, WT2, h, N);
  k_agg<<<ablk, 256, 0, stream>>>(h, bufB, offs, dinv, b2, h1, out, N, 1);
}